// Round 1
// baseline (3099.944 us; speedup 1.0000x reference)
//
#include <hip/hip_runtime.h>

#define NNODES 50000
#define NEDGES 800000
#define DIM    128
#define NGRAPH 512

__global__ void deg_kernel(const int* __restrict__ dst, float* __restrict__ deg, int nedges) {
    int t = blockIdx.x * blockDim.x + threadIdx.x;
    if (t < nedges) atomicAdd(&deg[dst[t]], 1.0f);
}

__global__ void rsqrt_kernel(float* __restrict__ deg, int n) {
    int t = blockIdx.x * blockDim.x + threadIdx.x;
    if (t < n) deg[t] = rsqrtf(deg[t] + 1.0f);
}

// Y[n][128] = X[n][128] @ W[128][128]; 8 rows per 256-thread block.
__global__ void __launch_bounds__(256) gemm128(const float* __restrict__ X,
                                               const float* __restrict__ W,
                                               float* __restrict__ Y) {
    __shared__ float Ws[DIM * DIM];
    __shared__ float Xs[8 * DIM];
    const float4* W4 = (const float4*)W;
    float4* Ws4 = (float4*)Ws;
    #pragma unroll
    for (int i = threadIdx.x; i < DIM * DIM / 4; i += 256) Ws4[i] = W4[i];
    ((float4*)Xs)[threadIdx.x] = ((const float4*)(X + (size_t)blockIdx.x * 8 * DIM))[threadIdx.x];
    __syncthreads();

    int rl = threadIdx.x >> 5;   // row within block (0..7)
    int q  = threadIdx.x & 31;   // float4 column group (0..31)
    const float* xr = Xs + rl * DIM;
    float4 acc = make_float4(0.f, 0.f, 0.f, 0.f);
    #pragma unroll 8
    for (int k = 0; k < DIM; ++k) {
        float xv = xr[k];
        float4 w = ((const float4*)(Ws + k * DIM))[q];
        acc.x = fmaf(xv, w.x, acc.x);
        acc.y = fmaf(xv, w.y, acc.y);
        acc.z = fmaf(xv, w.z, acc.z);
        acc.w = fmaf(xv, w.w, acc.w);
    }
    ((float4*)(Y + ((size_t)blockIdx.x * 8 + rl) * DIM))[q] = acc;
}

// For each edge e: agg[dst] += hw[src] * dis[src]*dis[dst].  32 threads/edge, float4 gather.
__global__ void edge_scatter(const float* __restrict__ hw, const int* __restrict__ src,
                             const int* __restrict__ dst, const float* __restrict__ dis,
                             float* __restrict__ agg, int nedges) {
    int t = blockIdx.x * blockDim.x + threadIdx.x;
    int nitems = nedges * 32;
    if (t >= nitems) return;
    int e = t >> 5, q = t & 31;
    int s = src[e], d = dst[e];
    float w = dis[s] * dis[d];
    float4 v = ((const float4*)(hw + (size_t)s * DIM))[q];
    float* ap = agg + (size_t)d * DIM + q * 4;
    atomicAdd(ap + 0, v.x * w);
    atomicAdd(ap + 1, v.y * w);
    atomicAdd(ap + 2, v.z * w);
    atomicAdd(ap + 3, v.w * w);
}

// agg = relu(agg + hw * dis[row]^2 + b[col])
__global__ void gcn_finalize(float* __restrict__ agg, const float* __restrict__ hw,
                             const float* __restrict__ dis, const float* __restrict__ b,
                             int nnodes) {
    int t = blockIdx.x * blockDim.x + threadIdx.x;
    int nitems = nnodes * 32;
    if (t >= nitems) return;
    int row = t >> 5, q = t & 31;
    float d2 = dis[row] * dis[row];
    float4 a  = ((const float4*)agg)[t];
    float4 h  = ((const float4*)hw)[t];
    float4 bb = ((const float4*)b)[q];
    a.x = fmaxf(a.x + h.x * d2 + bb.x, 0.f);
    a.y = fmaxf(a.y + h.y * d2 + bb.y, 0.f);
    a.z = fmaxf(a.z + h.z * d2 + bb.z, 0.f);
    a.w = fmaxf(a.w + h.w * d2 + bb.w, 0.f);
    ((float4*)agg)[t] = a;
}

// gnn_sum[g] += h2[node]; if x_source: cb_sum[g] += x[node]; counts.
__global__ void pool_kernel(const float* __restrict__ h, const float* __restrict__ x,
                            const int* __restrict__ batch, const int* __restrict__ xsrc,
                            float* __restrict__ gsum, float* __restrict__ csum,
                            float* __restrict__ gcnt, float* __restrict__ ccnt, int nnodes) {
    int t = blockIdx.x * blockDim.x + threadIdx.x;
    int nitems = nnodes * 32;
    if (t >= nitems) return;
    int row = t >> 5, q = t & 31;
    int g = batch[row];
    int is_src = xsrc[row];
    float4 hv = ((const float4*)h)[t];
    float* gp = gsum + (size_t)g * DIM + q * 4;
    atomicAdd(gp + 0, hv.x);
    atomicAdd(gp + 1, hv.y);
    atomicAdd(gp + 2, hv.z);
    atomicAdd(gp + 3, hv.w);
    if (is_src == 1) {
        float4 xv = ((const float4*)x)[t];
        float* cp = csum + (size_t)g * DIM + q * 4;
        atomicAdd(cp + 0, xv.x);
        atomicAdd(cp + 1, xv.y);
        atomicAdd(cp + 2, xv.z);
        atomicAdd(cp + 3, xv.w);
    }
    if (q == 0) {
        atomicAdd(&gcnt[g], 1.0f);
        if (is_src == 1) atomicAdd(&ccnt[g], 1.0f);
    }
}

// out[g] = concat(gsum/cnt, csum/ccnt) @ Wh + bh   (one 64-thread block per graph)
__global__ void head_kernel(const float* __restrict__ gsum, const float* __restrict__ csum,
                            const float* __restrict__ gcnt, const float* __restrict__ ccnt,
                            const float* __restrict__ Wh, const float* __restrict__ bh,
                            float* __restrict__ out) {
    int g = blockIdx.x;
    int lane = threadIdx.x;
    float gs = 1.0f / fmaxf(gcnt[g], 1.0f);
    float cs = 1.0f / fmaxf(ccnt[g], 1.0f);
    float a0 = 0.f, a1 = 0.f;
    #pragma unroll
    for (int k = lane; k < 2 * DIM; k += 64) {
        float e = (k < DIM) ? gsum[(size_t)g * DIM + k] * gs
                            : csum[(size_t)g * DIM + (k - DIM)] * cs;
        a0 = fmaf(e, Wh[k * 2 + 0], a0);
        a1 = fmaf(e, Wh[k * 2 + 1], a1);
    }
    #pragma unroll
    for (int off = 32; off; off >>= 1) {
        a0 += __shfl_down(a0, off);
        a1 += __shfl_down(a1, off);
    }
    if (lane == 0) {
        out[g * 2 + 0] = a0 + bh[0];
        out[g * 2 + 1] = a1 + bh[1];
    }
}

extern "C" void kernel_launch(void* const* d_in, const int* in_sizes, int n_in,
                              void* d_out, int out_size, void* d_ws, size_t ws_size,
                              hipStream_t stream) {
    const float* x    = (const float*)d_in[0];
    const int*   ei   = (const int*)d_in[1];       // [2, E] int32
    const int*   batch = (const int*)d_in[2];
    const int*   xsrc  = (const int*)d_in[3];
    const float* W1 = (const float*)d_in[4];
    const float* b1 = (const float*)d_in[5];
    const float* W2 = (const float*)d_in[6];
    const float* b2 = (const float*)d_in[7];
    const float* Wh = (const float*)d_in[8];
    const float* bh = (const float*)d_in[9];
    float* out = (float*)d_out;

    const int* src = ei;
    const int* dst = ei + NEDGES;

    float* ws   = (float*)d_ws;
    float* dis  = ws;                        // 50000 (deg then rsqrt in place)
    float* bufA = ws + 50048;                // 6.4M
    float* bufB = bufA + (size_t)NNODES * DIM;  // 6.4M
    float* gsum = bufB + (size_t)NNODES * DIM;  // 512*128
    float* csum = gsum + NGRAPH * DIM;          // 512*128
    float* gcnt = csum + NGRAPH * DIM;          // 512
    float* ccnt = gcnt + NGRAPH;                // 512

    const size_t nodefeat_bytes = (size_t)NNODES * DIM * sizeof(float);
    const int node_items  = NNODES * 32;
    const int edge_items  = NEDGES * 32;

    // --- degree / rsqrt ---
    hipMemsetAsync(dis, 0, NNODES * sizeof(float), stream);
    deg_kernel<<<(NEDGES + 255) / 256, 256, 0, stream>>>(dst, dis, NEDGES);
    rsqrt_kernel<<<(NNODES + 255) / 256, 256, 0, stream>>>(dis, NNODES);

    // --- layer 1: hw1 = x@W1 -> bufA; agg -> bufB; h1 = relu(...) in bufB ---
    gemm128<<<NNODES / 8, 256, 0, stream>>>(x, W1, bufA);
    hipMemsetAsync(bufB, 0, nodefeat_bytes, stream);
    edge_scatter<<<(edge_items + 255) / 256, 256, 0, stream>>>(bufA, src, dst, dis, bufB, NEDGES);
    gcn_finalize<<<(node_items + 255) / 256, 256, 0, stream>>>(bufB, bufA, dis, b1, NNODES);

    // --- layer 2: hw2 = h1@W2 -> bufA; agg -> bufB; h2 in bufB ---
    gemm128<<<NNODES / 8, 256, 0, stream>>>(bufB, W2, bufA);
    hipMemsetAsync(bufB, 0, nodefeat_bytes, stream);
    edge_scatter<<<(edge_items + 255) / 256, 256, 0, stream>>>(bufA, src, dst, dis, bufB, NEDGES);
    gcn_finalize<<<(node_items + 255) / 256, 256, 0, stream>>>(bufB, bufA, dis, b2, NNODES);

    // --- pooling ---
    hipMemsetAsync(gsum, 0, (2 * NGRAPH * DIM + 2 * NGRAPH) * sizeof(float), stream);
    pool_kernel<<<(node_items + 255) / 256, 256, 0, stream>>>(bufB, x, batch, xsrc,
                                                              gsum, csum, gcnt, ccnt, NNODES);

    // --- head ---
    head_kernel<<<NGRAPH, 64, 0, stream>>>(gsum, csum, gcnt, ccnt, Wh, bh, out);
}

// Round 2
// 423.911 us; speedup vs baseline: 7.3127x; 7.3127x over previous
//
#include <hip/hip_runtime.h>

#define NNODES 50000
#define NEDGES 800000
#define DIM    128
#define NGRAPH 512
#define NB_SCAN 196   // ceil(50000/256)

// ---------- degree (int) ----------
__global__ void deg_kernel(const int* __restrict__ dst, int* __restrict__ deg, int nedges) {
    int t = blockIdx.x * blockDim.x + threadIdx.x;
    if (t < nedges) atomicAdd(&deg[dst[t]], 1);
}

__global__ void rsqrt_kernel(const int* __restrict__ deg, float* __restrict__ dis, int n) {
    int t = blockIdx.x * blockDim.x + threadIdx.x;
    if (t < n) dis[t] = rsqrtf((float)deg[t] + 1.0f);
}

// ---------- exclusive scan (3 kernels) ----------
__global__ void scan_block(const int* __restrict__ in, int* __restrict__ out,
                           int* __restrict__ partials, int n) {
    __shared__ int s[256];
    int t = threadIdx.x;
    int gid = blockIdx.x * 256 + t;
    int v = (gid < n) ? in[gid] : 0;
    s[t] = v;
    __syncthreads();
    #pragma unroll
    for (int off = 1; off < 256; off <<= 1) {
        int u = (t >= off) ? s[t - off] : 0;
        __syncthreads();
        s[t] += u;
        __syncthreads();
    }
    if (gid < n) out[gid] = s[t] - v;          // exclusive within block
    if (t == 255) partials[blockIdx.x] = s[255];
}

__global__ void scan_partials(const int* __restrict__ in, int* __restrict__ out, int n) {
    __shared__ int s[256];
    int t = threadIdx.x;
    int v = (t < n) ? in[t] : 0;
    s[t] = v;
    __syncthreads();
    #pragma unroll
    for (int off = 1; off < 256; off <<= 1) {
        int u = (t >= off) ? s[t - off] : 0;
        __syncthreads();
        s[t] += u;
        __syncthreads();
    }
    if (t < n) out[t] = s[t] - v;
}

__global__ void scan_add(int* __restrict__ rowstart, const int* __restrict__ partials2, int n) {
    int gid = blockIdx.x * 256 + threadIdx.x;
    if (gid < n) rowstart[gid] += partials2[blockIdx.x];
    if (gid == 0) rowstart[n] = NEDGES;
}

// ---------- CSR fill ----------
__global__ void fill_csr(const int* __restrict__ src, const int* __restrict__ dst,
                         const int* __restrict__ rowstart, int* __restrict__ cursor,
                         int* __restrict__ csr_src, int nedges) {
    int e = blockIdx.x * blockDim.x + threadIdx.x;
    if (e >= nedges) return;
    int d = dst[e];
    int pos = atomicAdd(&cursor[d], 1);
    csr_src[rowstart[d] + pos] = src[e];
}

// ---------- dense 128x128 GEMM, 8 rows / 256-thread block ----------
__global__ void __launch_bounds__(256) gemm128(const float* __restrict__ X,
                                               const float* __restrict__ W,
                                               float* __restrict__ Y) {
    __shared__ float Ws[DIM * DIM];
    __shared__ float Xs[8 * DIM];
    const float4* W4 = (const float4*)W;
    float4* Ws4 = (float4*)Ws;
    #pragma unroll
    for (int i = threadIdx.x; i < DIM * DIM / 4; i += 256) Ws4[i] = W4[i];
    ((float4*)Xs)[threadIdx.x] = ((const float4*)(X + (size_t)blockIdx.x * 8 * DIM))[threadIdx.x];
    __syncthreads();

    int rl = threadIdx.x >> 5;
    int q  = threadIdx.x & 31;
    const float* xr = Xs + rl * DIM;
    float4 acc = make_float4(0.f, 0.f, 0.f, 0.f);
    #pragma unroll 8
    for (int k = 0; k < DIM; ++k) {
        float xv = xr[k];
        float4 w = ((const float4*)(Ws + k * DIM))[q];
        acc.x = fmaf(xv, w.x, acc.x);
        acc.y = fmaf(xv, w.y, acc.y);
        acc.z = fmaf(xv, w.z, acc.z);
        acc.w = fmaf(xv, w.w, acc.w);
    }
    ((float4*)(Y + ((size_t)blockIdx.x * 8 + rl) * DIM))[q] = acc;
}

// ---------- GCN aggregate (gather, no atomics) + self-loop + bias + relu ----------
__global__ void __launch_bounds__(256) gcn_gather(const float* __restrict__ hw,
                                                  const int* __restrict__ rowstart,
                                                  const int* __restrict__ csr_src,
                                                  const float* __restrict__ dis,
                                                  const float* __restrict__ b,
                                                  float* __restrict__ out) {
    int t = blockIdx.x * 256 + threadIdx.x;
    int d = t >> 5, q = t & 31;
    if (d >= NNODES) return;
    const float4* hw4 = (const float4*)hw;
    float dd = dis[d];
    float d2 = dd * dd;
    float4 hs = hw4[(size_t)d * 32 + q];
    float4 acc;
    acc.x = hs.x * d2; acc.y = hs.y * d2; acc.z = hs.z * d2; acc.w = hs.w * d2;
    int beg = rowstart[d], end = rowstart[d + 1];
    for (int i = beg; i < end; ++i) {
        int s = csr_src[i];
        float w = dis[s] * dd;
        float4 v = hw4[(size_t)s * 32 + q];
        acc.x = fmaf(v.x, w, acc.x);
        acc.y = fmaf(v.y, w, acc.y);
        acc.z = fmaf(v.z, w, acc.z);
        acc.w = fmaf(v.w, w, acc.w);
    }
    float4 bb = ((const float4*)b)[q];
    acc.x = fmaxf(acc.x + bb.x, 0.f);
    acc.y = fmaxf(acc.y + bb.y, 0.f);
    acc.z = fmaxf(acc.z + bb.z, 0.f);
    acc.w = fmaxf(acc.w + bb.w, 0.f);
    ((float4*)out)[(size_t)d * 32 + q] = acc;
}

// ---------- fused pooling + head (batch is sorted; no atomics) ----------
__device__ __forceinline__ int lower_bound_i(const int* __restrict__ a, int n, int v) {
    int lo = 0, hi = n;
    while (lo < hi) {
        int mid = (lo + hi) >> 1;
        if (a[mid] < v) lo = mid + 1; else hi = mid;
    }
    return lo;
}

__global__ void __launch_bounds__(256) pool_head(const float* __restrict__ h,
                                                 const float* __restrict__ x,
                                                 const int* __restrict__ batch,
                                                 const int* __restrict__ xsrc,
                                                 const float* __restrict__ Wh,
                                                 const float* __restrict__ bh,
                                                 float* __restrict__ out) {
    int t = blockIdx.x * 256 + threadIdx.x;
    int g = t >> 5, q = t & 31;
    if (g >= NGRAPH) return;
    int lo = lower_bound_i(batch, NNODES, g);
    int hi = lower_bound_i(batch, NNODES, g + 1);

    float4 ag = make_float4(0.f, 0.f, 0.f, 0.f);
    float4 ac = make_float4(0.f, 0.f, 0.f, 0.f);
    int sc = 0;
    const float4* h4 = (const float4*)h;
    const float4* x4 = (const float4*)x;
    for (int r = lo; r < hi; ++r) {
        float4 hv = h4[(size_t)r * 32 + q];
        ag.x += hv.x; ag.y += hv.y; ag.z += hv.z; ag.w += hv.w;
        if (xsrc[r] == 1) {
            float4 xv = x4[(size_t)r * 32 + q];
            ac.x += xv.x; ac.y += xv.y; ac.z += xv.z; ac.w += xv.w;
            sc++;
        }
    }
    float invg = 1.0f / fmaxf((float)(hi - lo), 1.0f);
    float invc = 1.0f / fmaxf((float)sc, 1.0f);

    const float2* Wh2 = (const float2*)Wh;   // Wh[k][0..1]
    float a0 = 0.f, a1 = 0.f;
    float ge[4] = {ag.x, ag.y, ag.z, ag.w};
    float ce[4] = {ac.x, ac.y, ac.z, ac.w};
    #pragma unroll
    for (int j = 0; j < 4; ++j) {
        float e1 = ge[j] * invg;
        float2 w1 = Wh2[q * 4 + j];
        a0 = fmaf(e1, w1.x, a0);
        a1 = fmaf(e1, w1.y, a1);
        float e2 = ce[j] * invc;
        float2 w2 = Wh2[DIM + q * 4 + j];
        a0 = fmaf(e2, w2.x, a0);
        a1 = fmaf(e2, w2.y, a1);
    }
    #pragma unroll
    for (int off = 16; off; off >>= 1) {
        a0 += __shfl_down(a0, off, 32);
        a1 += __shfl_down(a1, off, 32);
    }
    if (q == 0) {
        out[g * 2 + 0] = a0 + bh[0];
        out[g * 2 + 1] = a1 + bh[1];
    }
}

extern "C" void kernel_launch(void* const* d_in, const int* in_sizes, int n_in,
                              void* d_out, int out_size, void* d_ws, size_t ws_size,
                              hipStream_t stream) {
    const float* x     = (const float*)d_in[0];
    const int*   ei    = (const int*)d_in[1];       // [2, E] int32
    const int*   batch = (const int*)d_in[2];
    const int*   xsrc  = (const int*)d_in[3];
    const float* W1 = (const float*)d_in[4];
    const float* b1 = (const float*)d_in[5];
    const float* W2 = (const float*)d_in[6];
    const float* b2 = (const float*)d_in[7];
    const float* Wh = (const float*)d_in[8];
    const float* bh = (const float*)d_in[9];
    float* out = (float*)d_out;

    const int* src = ei;
    const int* dst = ei + NEDGES;

    // workspace layout (4-byte units)
    float* ws = (float*)d_ws;
    size_t off = 0;
    float* dis      = ws + off;        off += 50048;
    int*   rowstart = (int*)(ws + off); off += 50048;   // need 50001
    int*   tmpA     = (int*)(ws + off); off += 50048;   // degree, then cursor
    int*   part1    = (int*)(ws + off); off += 256;
    int*   part2    = (int*)(ws + off); off += 256;
    int*   csr_src  = (int*)(ws + off); off += 800000;
    float* bufA     = ws + off;        off += (size_t)NNODES * DIM;
    float* bufB     = ws + off;        off += (size_t)NNODES * DIM;

    // --- degree / norm / CSR build ---
    hipMemsetAsync(tmpA, 0, NNODES * sizeof(int), stream);
    deg_kernel<<<(NEDGES + 255) / 256, 256, 0, stream>>>(dst, tmpA, NEDGES);
    scan_block<<<NB_SCAN, 256, 0, stream>>>(tmpA, rowstart, part1, NNODES);
    scan_partials<<<1, 256, 0, stream>>>(part1, part2, NB_SCAN);
    scan_add<<<NB_SCAN, 256, 0, stream>>>(rowstart, part2, NNODES);
    rsqrt_kernel<<<(NNODES + 255) / 256, 256, 0, stream>>>(tmpA, dis, NNODES);
    hipMemsetAsync(tmpA, 0, NNODES * sizeof(int), stream);   // reuse as cursor
    fill_csr<<<(NEDGES + 255) / 256, 256, 0, stream>>>(src, dst, rowstart, tmpA, csr_src, NEDGES);

    // --- layer 1 ---
    gemm128<<<NNODES / 8, 256, 0, stream>>>(x, W1, bufA);
    gcn_gather<<<(NNODES * 32) / 256, 256, 0, stream>>>(bufA, rowstart, csr_src, dis, b1, bufB);

    // --- layer 2 ---
    gemm128<<<NNODES / 8, 256, 0, stream>>>(bufB, W2, bufA);
    gcn_gather<<<(NNODES * 32) / 256, 256, 0, stream>>>(bufA, rowstart, csr_src, dis, b2, bufB);

    // --- fused pooling + head ---
    pool_head<<<(NGRAPH * 32) / 256, 256, 0, stream>>>(bufB, x, batch, xsrc, Wh, bh, out);
}

// Round 3
// 306.403 us; speedup vs baseline: 10.1172x; 1.3835x over previous
//
#include <hip/hip_runtime.h>

#define NNODES 50000
#define NEDGES 800000
#define DIM    128
#define NGRAPH 512
#define NB_SCAN 196   // ceil(50000/256)

// ---------- degree (int) ----------
__global__ void deg_kernel(const int* __restrict__ dst, int* __restrict__ deg, int nedges) {
    int t = blockIdx.x * blockDim.x + threadIdx.x;
    if (t < nedges) atomicAdd(&deg[dst[t]], 1);
}

__global__ void rsqrt_kernel(const int* __restrict__ deg, float* __restrict__ dis, int n) {
    int t = blockIdx.x * blockDim.x + threadIdx.x;
    if (t < n) dis[t] = rsqrtf((float)deg[t] + 1.0f);
}

// ---------- exclusive scan (3 kernels) ----------
__global__ void scan_block(const int* __restrict__ in, int* __restrict__ out,
                           int* __restrict__ partials, int n) {
    __shared__ int s[256];
    int t = threadIdx.x;
    int gid = blockIdx.x * 256 + t;
    int v = (gid < n) ? in[gid] : 0;
    s[t] = v;
    __syncthreads();
    #pragma unroll
    for (int off = 1; off < 256; off <<= 1) {
        int u = (t >= off) ? s[t - off] : 0;
        __syncthreads();
        s[t] += u;
        __syncthreads();
    }
    if (gid < n) out[gid] = s[t] - v;          // exclusive within block
    if (t == 255) partials[blockIdx.x] = s[255];
}

__global__ void scan_partials(const int* __restrict__ in, int* __restrict__ out, int n) {
    __shared__ int s[256];
    int t = threadIdx.x;
    int v = (t < n) ? in[t] : 0;
    s[t] = v;
    __syncthreads();
    #pragma unroll
    for (int off = 1; off < 256; off <<= 1) {
        int u = (t >= off) ? s[t - off] : 0;
        __syncthreads();
        s[t] += u;
        __syncthreads();
    }
    if (t < n) out[t] = s[t] - v;
}

__global__ void scan_add(int* __restrict__ rowstart, const int* __restrict__ partials2, int n) {
    int gid = blockIdx.x * 256 + threadIdx.x;
    if (gid < n) rowstart[gid] += partials2[blockIdx.x];
    if (gid == 0) rowstart[n] = NEDGES;
}

// ---------- CSR fill ----------
__global__ void fill_csr(const int* __restrict__ src, const int* __restrict__ dst,
                         const int* __restrict__ rowstart, int* __restrict__ cursor,
                         int* __restrict__ csr_src, int nedges) {
    int e = blockIdx.x * blockDim.x + threadIdx.x;
    if (e >= nedges) return;
    int d = dst[e];
    int pos = atomicAdd(&cursor[d], 1);
    csr_src[rowstart[d] + pos] = src[e];
}

// ---------- register-tiled fp32 GEMM: Y[50000][128] = X @ W[128][128] ----------
// block = 256 threads -> 128x128 tile, thread computes 8x8. BK=32.
#define BK 32
#define XPAD 132
__global__ void __launch_bounds__(256) gemm_rt(const float* __restrict__ X,
                                               const float* __restrict__ W,
                                               float* __restrict__ Y) {
    __shared__ float Xs[BK * XPAD];   // transposed: Xs[k][row], padded
    __shared__ float Ws[BK * DIM];    // Ws[k][n], linear copy of W rows

    const int t  = threadIdx.x;
    const int tx = t & 15;            // 0..15 -> col group (8 cols)
    const int ty = t >> 4;            // 0..15 -> row group (8 rows)
    const int bm = blockIdx.x * 128;

    const int lr = t >> 3;            // 0..31: row within 32-row pass
    const int lc = t & 7;             // 0..7 : float4 within 128B k-segment

    float acc[8][8];
    #pragma unroll
    for (int i = 0; i < 8; ++i)
        #pragma unroll
        for (int j = 0; j < 8; ++j) acc[i][j] = 0.f;

    for (int k0 = 0; k0 < DIM; k0 += BK) {
        // load W slab: rows k0..k0+32 contiguous 16KB
        {
            const float4* Wg = (const float4*)(W + (size_t)k0 * DIM);
            float4* Wl = (float4*)Ws;
            #pragma unroll
            for (int i = 0; i < 4; ++i) Wl[t + 256 * i] = Wg[t + 256 * i];
        }
        // load X slab transposed: 4 passes of 32 rows
        #pragma unroll
        for (int p = 0; p < 4; ++p) {
            int row = p * 32 + lr;                       // 0..127
            int grow = bm + row;
            int crow = grow < NNODES ? grow : NNODES - 1;
            float4 v = *(const float4*)(X + (size_t)crow * DIM + k0 + lc * 4);
            Xs[(lc * 4 + 0) * XPAD + row] = v.x;
            Xs[(lc * 4 + 1) * XPAD + row] = v.y;
            Xs[(lc * 4 + 2) * XPAD + row] = v.z;
            Xs[(lc * 4 + 3) * XPAD + row] = v.w;
        }
        __syncthreads();

        #pragma unroll 4
        for (int kk = 0; kk < BK; ++kk) {
            float4 x0 = *(const float4*)(Xs + kk * XPAD + ty * 8);
            float4 x1 = *(const float4*)(Xs + kk * XPAD + ty * 8 + 4);
            float4 w0 = *(const float4*)(Ws + kk * DIM + tx * 8);
            float4 w1 = *(const float4*)(Ws + kk * DIM + tx * 8 + 4);
            float xv[8] = {x0.x, x0.y, x0.z, x0.w, x1.x, x1.y, x1.z, x1.w};
            float wv[8] = {w0.x, w0.y, w0.z, w0.w, w1.x, w1.y, w1.z, w1.w};
            #pragma unroll
            for (int i = 0; i < 8; ++i)
                #pragma unroll
                for (int j = 0; j < 8; ++j)
                    acc[i][j] = fmaf(xv[i], wv[j], acc[i][j]);
        }
        __syncthreads();
    }

    #pragma unroll
    for (int i = 0; i < 8; ++i) {
        int grow = bm + ty * 8 + i;
        if (grow < NNODES) {
            float* yp = Y + (size_t)grow * DIM + tx * 8;
            *(float4*)yp       = make_float4(acc[i][0], acc[i][1], acc[i][2], acc[i][3]);
            *(float4*)(yp + 4) = make_float4(acc[i][4], acc[i][5], acc[i][6], acc[i][7]);
        }
    }
}

// ---------- GCN aggregate (gather, no atomics) + self-loop + bias + relu ----------
__global__ void __launch_bounds__(256) gcn_gather(const float* __restrict__ hw,
                                                  const int* __restrict__ rowstart,
                                                  const int* __restrict__ csr_src,
                                                  const float* __restrict__ dis,
                                                  const float* __restrict__ b,
                                                  float* __restrict__ out) {
    int t = blockIdx.x * 256 + threadIdx.x;
    int d = t >> 5, q = t & 31;
    if (d >= NNODES) return;
    const float4* hw4 = (const float4*)hw;
    float dd = dis[d];
    float d2 = dd * dd;
    float4 hs = hw4[(size_t)d * 32 + q];
    float4 acc;
    acc.x = hs.x * d2; acc.y = hs.y * d2; acc.z = hs.z * d2; acc.w = hs.w * d2;
    int beg = rowstart[d], end = rowstart[d + 1];
    for (int i = beg; i < end; ++i) {
        int s = csr_src[i];
        float w = dis[s] * dd;
        float4 v = hw4[(size_t)s * 32 + q];
        acc.x = fmaf(v.x, w, acc.x);
        acc.y = fmaf(v.y, w, acc.y);
        acc.z = fmaf(v.z, w, acc.z);
        acc.w = fmaf(v.w, w, acc.w);
    }
    float4 bb = ((const float4*)b)[q];
    acc.x = fmaxf(acc.x + bb.x, 0.f);
    acc.y = fmaxf(acc.y + bb.y, 0.f);
    acc.z = fmaxf(acc.z + bb.z, 0.f);
    acc.w = fmaxf(acc.w + bb.w, 0.f);
    ((float4*)out)[(size_t)d * 32 + q] = acc;
}

// ---------- fused pooling + head: one 256-thread block per graph ----------
__device__ __forceinline__ int lower_bound_i(const int* __restrict__ a, int n, int v) {
    int lo = 0, hi = n;
    while (lo < hi) {
        int mid = (lo + hi) >> 1;
        if (a[mid] < v) lo = mid + 1; else hi = mid;
    }
    return lo;
}

__global__ void __launch_bounds__(256) pool_head(const float* __restrict__ h,
                                                 const float* __restrict__ x,
                                                 const int* __restrict__ batch,
                                                 const int* __restrict__ xsrc,
                                                 const float* __restrict__ Wh,
                                                 const float* __restrict__ bh,
                                                 float* __restrict__ out) {
    __shared__ float sAG[DIM];
    __shared__ float sAC[DIM];
    __shared__ int   sSC;
    int g   = blockIdx.x;
    int t   = threadIdx.x;
    int sub = t >> 5;      // 0..7 parallel row chains
    int q   = t & 31;

    if (t < DIM) { sAG[t] = 0.f; sAC[t] = 0.f; }
    if (t == 0) sSC = 0;
    __syncthreads();

    int lo = lower_bound_i(batch, NNODES, g);
    int hi = lower_bound_i(batch, NNODES, g + 1);

    float4 ag = make_float4(0.f, 0.f, 0.f, 0.f);
    float4 ac = make_float4(0.f, 0.f, 0.f, 0.f);
    int sc = 0;
    const float4* h4 = (const float4*)h;
    const float4* x4 = (const float4*)x;
    for (int r = lo + sub; r < hi; r += 8) {
        float4 hv = h4[(size_t)r * 32 + q];
        ag.x += hv.x; ag.y += hv.y; ag.z += hv.z; ag.w += hv.w;
        if (xsrc[r] == 1) {
            float4 xv = x4[(size_t)r * 32 + q];
            ac.x += xv.x; ac.y += xv.y; ac.z += xv.z; ac.w += xv.w;
            sc++;
        }
    }
    float* agp = sAG + q * 4;
    atomicAdd(agp + 0, ag.x); atomicAdd(agp + 1, ag.y);
    atomicAdd(agp + 2, ag.z); atomicAdd(agp + 3, ag.w);
    float* acp = sAC + q * 4;
    atomicAdd(acp + 0, ac.x); atomicAdd(acp + 1, ac.y);
    atomicAdd(acp + 2, ac.z); atomicAdd(acp + 3, ac.w);
    if (q == 0 && sc) atomicAdd(&sSC, sc);
    __syncthreads();

    if (t < 32) {
        float invg = 1.0f / fmaxf((float)(hi - lo), 1.0f);
        float invc = 1.0f / fmaxf((float)sSC, 1.0f);
        const float2* Wh2 = (const float2*)Wh;
        float a0 = 0.f, a1 = 0.f;
        #pragma unroll
        for (int j = 0; j < 4; ++j) {
            float e1 = sAG[t * 4 + j] * invg;
            float2 w1 = Wh2[t * 4 + j];
            a0 = fmaf(e1, w1.x, a0);
            a1 = fmaf(e1, w1.y, a1);
            float e2 = sAC[t * 4 + j] * invc;
            float2 w2 = Wh2[DIM + t * 4 + j];
            a0 = fmaf(e2, w2.x, a0);
            a1 = fmaf(e2, w2.y, a1);
        }
        #pragma unroll
        for (int off = 16; off; off >>= 1) {
            a0 += __shfl_down(a0, off, 32);
            a1 += __shfl_down(a1, off, 32);
        }
        if (t == 0) {
            out[g * 2 + 0] = a0 + bh[0];
            out[g * 2 + 1] = a1 + bh[1];
        }
    }
}

extern "C" void kernel_launch(void* const* d_in, const int* in_sizes, int n_in,
                              void* d_out, int out_size, void* d_ws, size_t ws_size,
                              hipStream_t stream) {
    const float* x     = (const float*)d_in[0];
    const int*   ei    = (const int*)d_in[1];       // [2, E] int32
    const int*   batch = (const int*)d_in[2];
    const int*   xsrc  = (const int*)d_in[3];
    const float* W1 = (const float*)d_in[4];
    const float* b1 = (const float*)d_in[5];
    const float* W2 = (const float*)d_in[6];
    const float* b2 = (const float*)d_in[7];
    const float* Wh = (const float*)d_in[8];
    const float* bh = (const float*)d_in[9];
    float* out = (float*)d_out;

    const int* src = ei;
    const int* dst = ei + NEDGES;

    // workspace layout (4-byte units)
    float* ws = (float*)d_ws;
    size_t off = 0;
    float* dis      = ws + off;        off += 50048;
    int*   rowstart = (int*)(ws + off); off += 50048;   // need 50001
    int*   tmpA     = (int*)(ws + off); off += 50048;   // degree, then cursor
    int*   part1    = (int*)(ws + off); off += 256;
    int*   part2    = (int*)(ws + off); off += 256;
    int*   csr_src  = (int*)(ws + off); off += 800000;
    float* bufA     = ws + off;        off += (size_t)NNODES * DIM;
    float* bufB     = ws + off;        off += (size_t)NNODES * DIM;

    // --- degree / norm / CSR build ---
    hipMemsetAsync(tmpA, 0, NNODES * sizeof(int), stream);
    deg_kernel<<<(NEDGES + 255) / 256, 256, 0, stream>>>(dst, tmpA, NEDGES);
    scan_block<<<NB_SCAN, 256, 0, stream>>>(tmpA, rowstart, part1, NNODES);
    scan_partials<<<1, 256, 0, stream>>>(part1, part2, NB_SCAN);
    scan_add<<<NB_SCAN, 256, 0, stream>>>(rowstart, part2, NNODES);
    rsqrt_kernel<<<(NNODES + 255) / 256, 256, 0, stream>>>(tmpA, dis, NNODES);
    hipMemsetAsync(tmpA, 0, NNODES * sizeof(int), stream);   // reuse as cursor
    fill_csr<<<(NEDGES + 255) / 256, 256, 0, stream>>>(src, dst, rowstart, tmpA, csr_src, NEDGES);

    const int ngemm = (NNODES + 127) / 128;

    // --- layer 1 ---
    gemm_rt<<<ngemm, 256, 0, stream>>>(x, W1, bufA);
    gcn_gather<<<(NNODES * 32) / 256, 256, 0, stream>>>(bufA, rowstart, csr_src, dis, b1, bufB);

    // --- layer 2 ---
    gemm_rt<<<ngemm, 256, 0, stream>>>(bufB, W2, bufA);
    gcn_gather<<<(NNODES * 32) / 256, 256, 0, stream>>>(bufA, rowstart, csr_src, dis, b2, bufB);

    // --- fused pooling + head ---
    pool_head<<<NGRAPH, 256, 0, stream>>>(bufB, x, batch, xsrc, Wh, bh, out);
}

// Round 4
// 298.989 us; speedup vs baseline: 10.3681x; 1.0248x over previous
//
#include <hip/hip_runtime.h>

#define NNODES 50000
#define NEDGES 800000
#define DIM    128
#define NGRAPH 512
#define NB_SCAN 196   // ceil(50000/256)

// ---------- degree (int) ----------
__global__ void deg_kernel(const int* __restrict__ dst, int* __restrict__ deg, int nedges) {
    int t = blockIdx.x * blockDim.x + threadIdx.x;
    if (t < nedges) atomicAdd(&deg[dst[t]], 1);
}

__global__ void rsqrt_kernel(const int* __restrict__ deg, float* __restrict__ dis, int n) {
    int t = blockIdx.x * blockDim.x + threadIdx.x;
    if (t < n) dis[t] = rsqrtf((float)deg[t] + 1.0f);
}

// ---------- exclusive scan (3 kernels) ----------
__global__ void scan_block(const int* __restrict__ in, int* __restrict__ out,
                           int* __restrict__ partials, int n) {
    __shared__ int s[256];
    int t = threadIdx.x;
    int gid = blockIdx.x * 256 + t;
    int v = (gid < n) ? in[gid] : 0;
    s[t] = v;
    __syncthreads();
    #pragma unroll
    for (int off = 1; off < 256; off <<= 1) {
        int u = (t >= off) ? s[t - off] : 0;
        __syncthreads();
        s[t] += u;
        __syncthreads();
    }
    if (gid < n) out[gid] = s[t] - v;          // exclusive within block
    if (t == 255) partials[blockIdx.x] = s[255];
}

__global__ void scan_partials(const int* __restrict__ in, int* __restrict__ out, int n) {
    __shared__ int s[256];
    int t = threadIdx.x;
    int v = (t < n) ? in[t] : 0;
    s[t] = v;
    __syncthreads();
    #pragma unroll
    for (int off = 1; off < 256; off <<= 1) {
        int u = (t >= off) ? s[t - off] : 0;
        __syncthreads();
        s[t] += u;
        __syncthreads();
    }
    if (t < n) out[t] = s[t] - v;
}

__global__ void scan_add(int* __restrict__ rowstart, const int* __restrict__ partials2, int n) {
    int gid = blockIdx.x * 256 + threadIdx.x;
    if (gid < n) rowstart[gid] += partials2[blockIdx.x];
    if (gid == 0) rowstart[n] = NEDGES;
}

// ---------- CSR fill ----------
__global__ void fill_csr(const int* __restrict__ src, const int* __restrict__ dst,
                         const int* __restrict__ rowstart, int* __restrict__ cursor,
                         int* __restrict__ csr_src, int nedges) {
    int e = blockIdx.x * blockDim.x + threadIdx.x;
    if (e >= nedges) return;
    int d = dst[e];
    int pos = atomicAdd(&cursor[d], 1);
    csr_src[rowstart[d] + pos] = src[e];
}

// ---------- register-tiled fp32 GEMM + scale epilogue ----------
// Y[n] = (X @ W)[n] * scale[n].  block = 256 threads -> 128x128 tile, thread 8x8.
#define BK 32
#define XPAD 132
__global__ void __launch_bounds__(256) gemm_rt(const float* __restrict__ X,
                                               const float* __restrict__ W,
                                               const float* __restrict__ scale,
                                               float* __restrict__ Y) {
    __shared__ float Xs[BK * XPAD];   // transposed: Xs[k][row], padded
    __shared__ float Ws[BK * DIM];    // Ws[k][n]

    const int t  = threadIdx.x;
    const int tx = t & 15;            // col group (8 cols)
    const int ty = t >> 4;            // row group (8 rows)
    const int bm = blockIdx.x * 128;

    const int lr = t >> 3;            // 0..31
    const int lc = t & 7;             // 0..7

    float acc[8][8];
    #pragma unroll
    for (int i = 0; i < 8; ++i)
        #pragma unroll
        for (int j = 0; j < 8; ++j) acc[i][j] = 0.f;

    for (int k0 = 0; k0 < DIM; k0 += BK) {
        {
            const float4* Wg = (const float4*)(W + (size_t)k0 * DIM);
            float4* Wl = (float4*)Ws;
            #pragma unroll
            for (int i = 0; i < 4; ++i) Wl[t + 256 * i] = Wg[t + 256 * i];
        }
        #pragma unroll
        for (int p = 0; p < 4; ++p) {
            int row = p * 32 + lr;
            int grow = bm + row;
            int crow = grow < NNODES ? grow : NNODES - 1;
            float4 v = *(const float4*)(X + (size_t)crow * DIM + k0 + lc * 4);
            Xs[(lc * 4 + 0) * XPAD + row] = v.x;
            Xs[(lc * 4 + 1) * XPAD + row] = v.y;
            Xs[(lc * 4 + 2) * XPAD + row] = v.z;
            Xs[(lc * 4 + 3) * XPAD + row] = v.w;
        }
        __syncthreads();

        #pragma unroll 4
        for (int kk = 0; kk < BK; ++kk) {
            float4 x0 = *(const float4*)(Xs + kk * XPAD + ty * 8);
            float4 x1 = *(const float4*)(Xs + kk * XPAD + ty * 8 + 4);
            float4 w0 = *(const float4*)(Ws + kk * DIM + tx * 8);
            float4 w1 = *(const float4*)(Ws + kk * DIM + tx * 8 + 4);
            float xv[8] = {x0.x, x0.y, x0.z, x0.w, x1.x, x1.y, x1.z, x1.w};
            float wv[8] = {w0.x, w0.y, w0.z, w0.w, w1.x, w1.y, w1.z, w1.w};
            #pragma unroll
            for (int i = 0; i < 8; ++i)
                #pragma unroll
                for (int j = 0; j < 8; ++j)
                    acc[i][j] = fmaf(xv[i], wv[j], acc[i][j]);
        }
        __syncthreads();
    }

    #pragma unroll
    for (int i = 0; i < 8; ++i) {
        int grow = bm + ty * 8 + i;
        if (grow < NNODES) {
            float s = scale[grow];
            float* yp = Y + (size_t)grow * DIM + tx * 8;
            *(float4*)yp       = make_float4(acc[i][0] * s, acc[i][1] * s,
                                             acc[i][2] * s, acc[i][3] * s);
            *(float4*)(yp + 4) = make_float4(acc[i][4] * s, acc[i][5] * s,
                                             acc[i][6] * s, acc[i][7] * s);
        }
    }
}

// ---------- GCN aggregate: pure gather-sum of pre-scaled rows, 8-way MLP ----------
// out[d] = relu(dis[d] * (sum_{s in N(d)} hw'[s] + hw'[d]) + b)
__global__ void __launch_bounds__(256) gcn_gather(const float* __restrict__ hw,
                                                  const int* __restrict__ rowstart,
                                                  const int* __restrict__ csr_src,
                                                  const float* __restrict__ dis,
                                                  const float* __restrict__ b,
                                                  float* __restrict__ out) {
    int t = blockIdx.x * 256 + threadIdx.x;
    int d = t >> 5, q = t & 31;
    if (d >= NNODES) return;
    const float4* hw4 = (const float4*)hw;

    float4 a0 = hw4[(size_t)d * 32 + q];   // self-loop (pre-scaled)
    float4 a1 = make_float4(0.f, 0.f, 0.f, 0.f);
    float4 a2 = make_float4(0.f, 0.f, 0.f, 0.f);
    float4 a3 = make_float4(0.f, 0.f, 0.f, 0.f);
    float4 a4 = make_float4(0.f, 0.f, 0.f, 0.f);
    float4 a5 = make_float4(0.f, 0.f, 0.f, 0.f);
    float4 a6 = make_float4(0.f, 0.f, 0.f, 0.f);
    float4 a7 = make_float4(0.f, 0.f, 0.f, 0.f);

    int beg = rowstart[d], end = rowstart[d + 1];
    int i = beg;
    for (; i + 8 <= end; i += 8) {
        int s0 = csr_src[i + 0], s1 = csr_src[i + 1];
        int s2 = csr_src[i + 2], s3 = csr_src[i + 3];
        int s4 = csr_src[i + 4], s5 = csr_src[i + 5];
        int s6 = csr_src[i + 6], s7 = csr_src[i + 7];
        float4 v0 = hw4[(size_t)s0 * 32 + q];
        float4 v1 = hw4[(size_t)s1 * 32 + q];
        float4 v2 = hw4[(size_t)s2 * 32 + q];
        float4 v3 = hw4[(size_t)s3 * 32 + q];
        float4 v4 = hw4[(size_t)s4 * 32 + q];
        float4 v5 = hw4[(size_t)s5 * 32 + q];
        float4 v6 = hw4[(size_t)s6 * 32 + q];
        float4 v7 = hw4[(size_t)s7 * 32 + q];
        a0.x += v0.x; a0.y += v0.y; a0.z += v0.z; a0.w += v0.w;
        a1.x += v1.x; a1.y += v1.y; a1.z += v1.z; a1.w += v1.w;
        a2.x += v2.x; a2.y += v2.y; a2.z += v2.z; a2.w += v2.w;
        a3.x += v3.x; a3.y += v3.y; a3.z += v3.z; a3.w += v3.w;
        a4.x += v4.x; a4.y += v4.y; a4.z += v4.z; a4.w += v4.w;
        a5.x += v5.x; a5.y += v5.y; a5.z += v5.z; a5.w += v5.w;
        a6.x += v6.x; a6.y += v6.y; a6.z += v6.z; a6.w += v6.w;
        a7.x += v7.x; a7.y += v7.y; a7.z += v7.z; a7.w += v7.w;
    }
    for (; i + 2 <= end; i += 2) {
        int s0 = csr_src[i + 0], s1 = csr_src[i + 1];
        float4 v0 = hw4[(size_t)s0 * 32 + q];
        float4 v1 = hw4[(size_t)s1 * 32 + q];
        a0.x += v0.x; a0.y += v0.y; a0.z += v0.z; a0.w += v0.w;
        a1.x += v1.x; a1.y += v1.y; a1.z += v1.z; a1.w += v1.w;
    }
    if (i < end) {
        float4 v0 = hw4[(size_t)csr_src[i] * 32 + q];
        a0.x += v0.x; a0.y += v0.y; a0.z += v0.z; a0.w += v0.w;
    }

    a0.x += a1.x + a2.x + a3.x + a4.x + a5.x + a6.x + a7.x;
    a0.y += a1.y + a2.y + a3.y + a4.y + a5.y + a6.y + a7.y;
    a0.z += a1.z + a2.z + a3.z + a4.z + a5.z + a6.z + a7.z;
    a0.w += a1.w + a2.w + a3.w + a4.w + a5.w + a6.w + a7.w;

    float dd = dis[d];
    float4 bb = ((const float4*)b)[q];
    a0.x = fmaxf(fmaf(a0.x, dd, bb.x), 0.f);
    a0.y = fmaxf(fmaf(a0.y, dd, bb.y), 0.f);
    a0.z = fmaxf(fmaf(a0.z, dd, bb.z), 0.f);
    a0.w = fmaxf(fmaf(a0.w, dd, bb.w), 0.f);
    ((float4*)out)[(size_t)d * 32 + q] = a0;
}

// ---------- fused pooling + head: one 256-thread block per graph ----------
__device__ __forceinline__ int lower_bound_i(const int* __restrict__ a, int n, int v) {
    int lo = 0, hi = n;
    while (lo < hi) {
        int mid = (lo + hi) >> 1;
        if (a[mid] < v) lo = mid + 1; else hi = mid;
    }
    return lo;
}

__global__ void __launch_bounds__(256) pool_head(const float* __restrict__ h,
                                                 const float* __restrict__ x,
                                                 const int* __restrict__ batch,
                                                 const int* __restrict__ xsrc,
                                                 const float* __restrict__ Wh,
                                                 const float* __restrict__ bh,
                                                 float* __restrict__ out) {
    __shared__ float sAG[DIM];
    __shared__ float sAC[DIM];
    __shared__ int   sSC;
    int g   = blockIdx.x;
    int t   = threadIdx.x;
    int sub = t >> 5;      // 0..7 parallel row chains
    int q   = t & 31;

    if (t < DIM) { sAG[t] = 0.f; sAC[t] = 0.f; }
    if (t == 0) sSC = 0;
    __syncthreads();

    int lo = lower_bound_i(batch, NNODES, g);
    int hi = lower_bound_i(batch, NNODES, g + 1);

    float4 ag = make_float4(0.f, 0.f, 0.f, 0.f);
    float4 ac = make_float4(0.f, 0.f, 0.f, 0.f);
    int sc = 0;
    const float4* h4 = (const float4*)h;
    const float4* x4 = (const float4*)x;
    for (int r = lo + sub; r < hi; r += 8) {
        float4 hv = h4[(size_t)r * 32 + q];
        ag.x += hv.x; ag.y += hv.y; ag.z += hv.z; ag.w += hv.w;
        if (xsrc[r] == 1) {
            float4 xv = x4[(size_t)r * 32 + q];
            ac.x += xv.x; ac.y += xv.y; ac.z += xv.z; ac.w += xv.w;
            sc++;
        }
    }
    float* agp = sAG + q * 4;
    atomicAdd(agp + 0, ag.x); atomicAdd(agp + 1, ag.y);
    atomicAdd(agp + 2, ag.z); atomicAdd(agp + 3, ag.w);
    float* acp = sAC + q * 4;
    atomicAdd(acp + 0, ac.x); atomicAdd(acp + 1, ac.y);
    atomicAdd(acp + 2, ac.z); atomicAdd(acp + 3, ac.w);
    if (q == 0 && sc) atomicAdd(&sSC, sc);
    __syncthreads();

    if (t < 32) {
        float invg = 1.0f / fmaxf((float)(hi - lo), 1.0f);
        float invc = 1.0f / fmaxf((float)sSC, 1.0f);
        const float2* Wh2 = (const float2*)Wh;
        float a0 = 0.f, a1 = 0.f;
        #pragma unroll
        for (int j = 0; j < 4; ++j) {
            float e1 = sAG[t * 4 + j] * invg;
            float2 w1 = Wh2[t * 4 + j];
            a0 = fmaf(e1, w1.x, a0);
            a1 = fmaf(e1, w1.y, a1);
            float e2 = sAC[t * 4 + j] * invc;
            float2 w2 = Wh2[DIM + t * 4 + j];
            a0 = fmaf(e2, w2.x, a0);
            a1 = fmaf(e2, w2.y, a1);
        }
        #pragma unroll
        for (int off = 16; off; off >>= 1) {
            a0 += __shfl_down(a0, off, 32);
            a1 += __shfl_down(a1, off, 32);
        }
        if (t == 0) {
            out[g * 2 + 0] = a0 + bh[0];
            out[g * 2 + 1] = a1 + bh[1];
        }
    }
}

extern "C" void kernel_launch(void* const* d_in, const int* in_sizes, int n_in,
                              void* d_out, int out_size, void* d_ws, size_t ws_size,
                              hipStream_t stream) {
    const float* x     = (const float*)d_in[0];
    const int*   ei    = (const int*)d_in[1];       // [2, E] int32
    const int*   batch = (const int*)d_in[2];
    const int*   xsrc  = (const int*)d_in[3];
    const float* W1 = (const float*)d_in[4];
    const float* b1 = (const float*)d_in[5];
    const float* W2 = (const float*)d_in[6];
    const float* b2 = (const float*)d_in[7];
    const float* Wh = (const float*)d_in[8];
    const float* bh = (const float*)d_in[9];
    float* out = (float*)d_out;

    const int* src = ei;
    const int* dst = ei + NEDGES;

    // workspace layout (4-byte units)
    float* ws = (float*)d_ws;
    size_t off = 0;
    float* dis      = ws + off;        off += 50048;
    int*   rowstart = (int*)(ws + off); off += 50048;   // need 50001
    int*   tmpA     = (int*)(ws + off); off += 50048;   // degree, then cursor
    int*   part1    = (int*)(ws + off); off += 256;
    int*   part2    = (int*)(ws + off); off += 256;
    int*   csr_src  = (int*)(ws + off); off += 800000;
    float* bufA     = ws + off;        off += (size_t)NNODES * DIM;
    float* bufB     = ws + off;        off += (size_t)NNODES * DIM;

    // --- degree / norm / CSR build ---
    hipMemsetAsync(tmpA, 0, NNODES * sizeof(int), stream);
    deg_kernel<<<(NEDGES + 255) / 256, 256, 0, stream>>>(dst, tmpA, NEDGES);
    scan_block<<<NB_SCAN, 256, 0, stream>>>(tmpA, rowstart, part1, NNODES);
    scan_partials<<<1, 256, 0, stream>>>(part1, part2, NB_SCAN);
    scan_add<<<NB_SCAN, 256, 0, stream>>>(rowstart, part2, NNODES);
    rsqrt_kernel<<<(NNODES + 255) / 256, 256, 0, stream>>>(tmpA, dis, NNODES);
    hipMemsetAsync(tmpA, 0, NNODES * sizeof(int), stream);   // reuse as cursor
    fill_csr<<<(NEDGES + 255) / 256, 256, 0, stream>>>(src, dst, rowstart, tmpA, csr_src, NEDGES);

    const int ngemm = (NNODES + 127) / 128;

    // --- layer 1: hw1' = (x@W1)*dis -> bufA; h1 -> bufB ---
    gemm_rt<<<ngemm, 256, 0, stream>>>(x, W1, dis, bufA);
    gcn_gather<<<(NNODES * 32) / 256, 256, 0, stream>>>(bufA, rowstart, csr_src, dis, b1, bufB);

    // --- layer 2 ---
    gemm_rt<<<ngemm, 256, 0, stream>>>(bufB, W2, dis, bufA);
    gcn_gather<<<(NNODES * 32) / 256, 256, 0, stream>>>(bufA, rowstart, csr_src, dis, b2, bufB);

    // --- fused pooling + head ---
    pool_head<<<NGRAPH, 256, 0, stream>>>(bufB, x, batch, xsrc, Wh, bh, out);
}

// Round 5
// 254.119 us; speedup vs baseline: 12.1988x; 1.1766x over previous
//
#include <hip/hip_runtime.h>
#include <hip/hip_fp16.h>

#define NNODES 50000
#define NEDGES 800000
#define DIM    128
#define NGRAPH 512
#define NB_SCAN 196   // ceil(50000/256)

// ---------- degree (int) ----------
__global__ void deg_kernel(const int* __restrict__ dst, int* __restrict__ deg, int nedges) {
    int t = blockIdx.x * blockDim.x + threadIdx.x;
    if (t < nedges) atomicAdd(&deg[dst[t]], 1);
}

// ---------- exclusive scan (3 kernels); scan_block also emits dis = rsqrt(deg+1) ----------
__global__ void scan_block(const int* __restrict__ in, int* __restrict__ out,
                           int* __restrict__ partials, float* __restrict__ dis, int n) {
    __shared__ int s[256];
    int t = threadIdx.x;
    int gid = blockIdx.x * 256 + t;
    int v = (gid < n) ? in[gid] : 0;
    if (gid < n) dis[gid] = rsqrtf((float)v + 1.0f);
    s[t] = v;
    __syncthreads();
    #pragma unroll
    for (int off = 1; off < 256; off <<= 1) {
        int u = (t >= off) ? s[t - off] : 0;
        __syncthreads();
        s[t] += u;
        __syncthreads();
    }
    if (gid < n) out[gid] = s[t] - v;          // exclusive within block
    if (t == 255) partials[blockIdx.x] = s[255];
}

__global__ void scan_partials(const int* __restrict__ in, int* __restrict__ out, int n) {
    __shared__ int s[256];
    int t = threadIdx.x;
    int v = (t < n) ? in[t] : 0;
    s[t] = v;
    __syncthreads();
    #pragma unroll
    for (int off = 1; off < 256; off <<= 1) {
        int u = (t >= off) ? s[t - off] : 0;
        __syncthreads();
        s[t] += u;
        __syncthreads();
    }
    if (t < n) out[t] = s[t] - v;
}

// rowstart += partials2; cursor = rowstart (absolute); rowstart[n] = NEDGES
__global__ void scan_add(int* __restrict__ rowstart, const int* __restrict__ partials2,
                         int* __restrict__ cursor, int n) {
    int gid = blockIdx.x * 256 + threadIdx.x;
    if (gid < n) {
        int v = rowstart[gid] + partials2[blockIdx.x];
        rowstart[gid] = v;
        cursor[gid] = v;
    }
    if (gid == 0) rowstart[n] = NEDGES;
}

// ---------- CSR fill (absolute cursor) ----------
__global__ void fill_csr(const int* __restrict__ src, const int* __restrict__ dst,
                         int* __restrict__ cursor, int* __restrict__ csr_src, int nedges) {
    int e = blockIdx.x * blockDim.x + threadIdx.x;
    if (e >= nedges) return;
    int d = dst[e];
    int pos = atomicAdd(&cursor[d], 1);
    csr_src[pos] = src[e];
}

// ---------- register-tiled fp32 GEMM, fp16-packed scaled output ----------
// Yh[n] = fp16((X @ W)[n] * scale[n]).  block=256 -> 128x128 tile, thread 8x8.
#define BK 32
#define XPAD 132
__global__ void __launch_bounds__(256) gemm_rt(const float* __restrict__ X,
                                               const float* __restrict__ W,
                                               const float* __restrict__ scale,
                                               __half* __restrict__ Yh) {
    __shared__ float Xs[BK * XPAD];   // transposed: Xs[k][row], padded
    __shared__ float Ws[BK * DIM];    // Ws[k][n]

    const int t  = threadIdx.x;
    const int tx = t & 15;            // col group (8 cols)
    const int ty = t >> 4;            // row group (8 rows)
    const int bm = blockIdx.x * 128;

    const int lr = t >> 3;            // 0..31
    const int lc = t & 7;             // 0..7

    float acc[8][8];
    #pragma unroll
    for (int i = 0; i < 8; ++i)
        #pragma unroll
        for (int j = 0; j < 8; ++j) acc[i][j] = 0.f;

    for (int k0 = 0; k0 < DIM; k0 += BK) {
        {
            const float4* Wg = (const float4*)(W + (size_t)k0 * DIM);
            float4* Wl = (float4*)Ws;
            #pragma unroll
            for (int i = 0; i < 4; ++i) Wl[t + 256 * i] = Wg[t + 256 * i];
        }
        #pragma unroll
        for (int p = 0; p < 4; ++p) {
            int row = p * 32 + lr;
            int grow = bm + row;
            int crow = grow < NNODES ? grow : NNODES - 1;
            float4 v = *(const float4*)(X + (size_t)crow * DIM + k0 + lc * 4);
            Xs[(lc * 4 + 0) * XPAD + row] = v.x;
            Xs[(lc * 4 + 1) * XPAD + row] = v.y;
            Xs[(lc * 4 + 2) * XPAD + row] = v.z;
            Xs[(lc * 4 + 3) * XPAD + row] = v.w;
        }
        __syncthreads();

        #pragma unroll 4
        for (int kk = 0; kk < BK; ++kk) {
            float4 x0 = *(const float4*)(Xs + kk * XPAD + ty * 8);
            float4 x1 = *(const float4*)(Xs + kk * XPAD + ty * 8 + 4);
            float4 w0 = *(const float4*)(Ws + kk * DIM + tx * 8);
            float4 w1 = *(const float4*)(Ws + kk * DIM + tx * 8 + 4);
            float xv[8] = {x0.x, x0.y, x0.z, x0.w, x1.x, x1.y, x1.z, x1.w};
            float wv[8] = {w0.x, w0.y, w0.z, w0.w, w1.x, w1.y, w1.z, w1.w};
            #pragma unroll
            for (int i = 0; i < 8; ++i)
                #pragma unroll
                for (int j = 0; j < 8; ++j)
                    acc[i][j] = fmaf(xv[i], wv[j], acc[i][j]);
        }
        __syncthreads();
    }

    #pragma unroll
    for (int i = 0; i < 8; ++i) {
        int grow = bm + ty * 8 + i;
        if (grow < NNODES) {
            float s = scale[grow];
            __half2 p0 = __floats2half2_rn(acc[i][0] * s, acc[i][1] * s);
            __half2 p1 = __floats2half2_rn(acc[i][2] * s, acc[i][3] * s);
            __half2 p2 = __floats2half2_rn(acc[i][4] * s, acc[i][5] * s);
            __half2 p3 = __floats2half2_rn(acc[i][6] * s, acc[i][7] * s);
            uint4 pk;
            pk.x = *(unsigned*)&p0; pk.y = *(unsigned*)&p1;
            pk.z = *(unsigned*)&p2; pk.w = *(unsigned*)&p3;
            *(uint4*)(Yh + (size_t)grow * DIM + tx * 8) = pk;
        }
    }
}

// ---------- GCN aggregate: fp16 gather-sum, fp32 accumulate ----------
// out[d] = relu(dis[d] * (sum_{s in N(d)} hw'[s] + hw'[d]) + b)
__device__ __forceinline__ void acc_add(float4& a, uint2 u) {
    float2 f0 = __half22float2(*(__half2*)&u.x);
    float2 f1 = __half22float2(*(__half2*)&u.y);
    a.x += f0.x; a.y += f0.y; a.z += f1.x; a.w += f1.y;
}

__global__ void __launch_bounds__(256) gcn_gather(const __half* __restrict__ hwh,
                                                  const int* __restrict__ rowstart,
                                                  const int* __restrict__ csr_src,
                                                  const float* __restrict__ dis,
                                                  const float* __restrict__ b,
                                                  float* __restrict__ out) {
    int t = blockIdx.x * 256 + threadIdx.x;
    int d = t >> 5, q = t & 31;
    if (d >= NNODES) return;
    const uint2* hw8 = (const uint2*)hwh;   // 32 uint2 per 128-half row

    float4 a0 = make_float4(0.f, 0.f, 0.f, 0.f);
    float4 a1 = make_float4(0.f, 0.f, 0.f, 0.f);
    float4 a2 = make_float4(0.f, 0.f, 0.f, 0.f);
    float4 a3 = make_float4(0.f, 0.f, 0.f, 0.f);
    float4 a4 = make_float4(0.f, 0.f, 0.f, 0.f);
    float4 a5 = make_float4(0.f, 0.f, 0.f, 0.f);
    float4 a6 = make_float4(0.f, 0.f, 0.f, 0.f);
    float4 a7 = make_float4(0.f, 0.f, 0.f, 0.f);

    acc_add(a0, hw8[(size_t)d * 32 + q]);   // self-loop (pre-scaled)

    int beg = rowstart[d], end = rowstart[d + 1];
    int i = beg;
    for (; i + 8 <= end; i += 8) {
        int s0 = csr_src[i + 0], s1 = csr_src[i + 1];
        int s2 = csr_src[i + 2], s3 = csr_src[i + 3];
        int s4 = csr_src[i + 4], s5 = csr_src[i + 5];
        int s6 = csr_src[i + 6], s7 = csr_src[i + 7];
        uint2 v0 = hw8[(size_t)s0 * 32 + q];
        uint2 v1 = hw8[(size_t)s1 * 32 + q];
        uint2 v2 = hw8[(size_t)s2 * 32 + q];
        uint2 v3 = hw8[(size_t)s3 * 32 + q];
        uint2 v4 = hw8[(size_t)s4 * 32 + q];
        uint2 v5 = hw8[(size_t)s5 * 32 + q];
        uint2 v6 = hw8[(size_t)s6 * 32 + q];
        uint2 v7 = hw8[(size_t)s7 * 32 + q];
        acc_add(a0, v0); acc_add(a1, v1); acc_add(a2, v2); acc_add(a3, v3);
        acc_add(a4, v4); acc_add(a5, v5); acc_add(a6, v6); acc_add(a7, v7);
    }
    for (; i + 2 <= end; i += 2) {
        uint2 v0 = hw8[(size_t)csr_src[i + 0] * 32 + q];
        uint2 v1 = hw8[(size_t)csr_src[i + 1] * 32 + q];
        acc_add(a0, v0); acc_add(a1, v1);
    }
    if (i < end) acc_add(a0, hw8[(size_t)csr_src[i] * 32 + q]);

    a0.x += a1.x + a2.x + a3.x + a4.x + a5.x + a6.x + a7.x;
    a0.y += a1.y + a2.y + a3.y + a4.y + a5.y + a6.y + a7.y;
    a0.z += a1.z + a2.z + a3.z + a4.z + a5.z + a6.z + a7.z;
    a0.w += a1.w + a2.w + a3.w + a4.w + a5.w + a6.w + a7.w;

    float dd = dis[d];
    float4 bb = ((const float4*)b)[q];
    a0.x = fmaxf(fmaf(a0.x, dd, bb.x), 0.f);
    a0.y = fmaxf(fmaf(a0.y, dd, bb.y), 0.f);
    a0.z = fmaxf(fmaf(a0.z, dd, bb.z), 0.f);
    a0.w = fmaxf(fmaf(a0.w, dd, bb.w), 0.f);
    ((float4*)out)[(size_t)d * 32 + q] = a0;
}

// ---------- fused pooling + head: one 256-thread block per graph ----------
__device__ __forceinline__ int lower_bound_i(const int* __restrict__ a, int n, int v) {
    int lo = 0, hi = n;
    while (lo < hi) {
        int mid = (lo + hi) >> 1;
        if (a[mid] < v) lo = mid + 1; else hi = mid;
    }
    return lo;
}

__global__ void __launch_bounds__(256) pool_head(const float* __restrict__ h,
                                                 const float* __restrict__ x,
                                                 const int* __restrict__ batch,
                                                 const int* __restrict__ xsrc,
                                                 const float* __restrict__ Wh,
                                                 const float* __restrict__ bh,
                                                 float* __restrict__ out) {
    __shared__ float sAG[DIM];
    __shared__ float sAC[DIM];
    __shared__ int   sSC;
    int g   = blockIdx.x;
    int t   = threadIdx.x;
    int sub = t >> 5;      // 0..7 parallel row chains
    int q   = t & 31;

    if (t < DIM) { sAG[t] = 0.f; sAC[t] = 0.f; }
    if (t == 0) sSC = 0;
    __syncthreads();

    int lo = lower_bound_i(batch, NNODES, g);
    int hi = lower_bound_i(batch, NNODES, g + 1);

    float4 ag = make_float4(0.f, 0.f, 0.f, 0.f);
    float4 ac = make_float4(0.f, 0.f, 0.f, 0.f);
    int sc = 0;
    const float4* h4 = (const float4*)h;
    const float4* x4 = (const float4*)x;
    for (int r = lo + sub; r < hi; r += 8) {
        float4 hv = h4[(size_t)r * 32 + q];
        ag.x += hv.x; ag.y += hv.y; ag.z += hv.z; ag.w += hv.w;
        if (xsrc[r] == 1) {
            float4 xv = x4[(size_t)r * 32 + q];
            ac.x += xv.x; ac.y += xv.y; ac.z += xv.z; ac.w += xv.w;
            sc++;
        }
    }
    float* agp = sAG + q * 4;
    atomicAdd(agp + 0, ag.x); atomicAdd(agp + 1, ag.y);
    atomicAdd(agp + 2, ag.z); atomicAdd(agp + 3, ag.w);
    float* acp = sAC + q * 4;
    atomicAdd(acp + 0, ac.x); atomicAdd(acp + 1, ac.y);
    atomicAdd(acp + 2, ac.z); atomicAdd(acp + 3, ac.w);
    if (q == 0 && sc) atomicAdd(&sSC, sc);
    __syncthreads();

    if (t < 32) {
        float invg = 1.0f / fmaxf((float)(hi - lo), 1.0f);
        float invc = 1.0f / fmaxf((float)sSC, 1.0f);
        const float2* Wh2 = (const float2*)Wh;
        float a0 = 0.f, a1 = 0.f;
        #pragma unroll
        for (int j = 0; j < 4; ++j) {
            float e1 = sAG[t * 4 + j] * invg;
            float2 w1 = Wh2[t * 4 + j];
            a0 = fmaf(e1, w1.x, a0);
            a1 = fmaf(e1, w1.y, a1);
            float e2 = sAC[t * 4 + j] * invc;
            float2 w2 = Wh2[DIM + t * 4 + j];
            a0 = fmaf(e2, w2.x, a0);
            a1 = fmaf(e2, w2.y, a1);
        }
        #pragma unroll
        for (int off = 16; off; off >>= 1) {
            a0 += __shfl_down(a0, off, 32);
            a1 += __shfl_down(a1, off, 32);
        }
        if (t == 0) {
            out[g * 2 + 0] = a0 + bh[0];
            out[g * 2 + 1] = a1 + bh[1];
        }
    }
}

extern "C" void kernel_launch(void* const* d_in, const int* in_sizes, int n_in,
                              void* d_out, int out_size, void* d_ws, size_t ws_size,
                              hipStream_t stream) {
    const float* x     = (const float*)d_in[0];
    const int*   ei    = (const int*)d_in[1];       // [2, E] int32
    const int*   batch = (const int*)d_in[2];
    const int*   xsrc  = (const int*)d_in[3];
    const float* W1 = (const float*)d_in[4];
    const float* b1 = (const float*)d_in[5];
    const float* W2 = (const float*)d_in[6];
    const float* b2 = (const float*)d_in[7];
    const float* Wh = (const float*)d_in[8];
    const float* bh = (const float*)d_in[9];
    float* out = (float*)d_out;

    const int* src = ei;
    const int* dst = ei + NEDGES;

    // workspace layout (4-byte units)
    float* ws = (float*)d_ws;
    size_t off = 0;
    float*  dis      = ws + off;         off += 50048;
    int*    rowstart = (int*)(ws + off); off += 50048;   // need 50001
    int*    deg      = (int*)(ws + off); off += 50048;
    int*    cursor   = (int*)(ws + off); off += 50048;
    int*    part1    = (int*)(ws + off); off += 256;
    int*    part2    = (int*)(ws + off); off += 256;
    int*    csr_src  = (int*)(ws + off); off += 800000;
    __half* hwh      = (__half*)(ws + off); off += (size_t)NNODES * DIM / 2;
    float*  bufB     = ws + off;         off += (size_t)NNODES * DIM;

    // --- degree / norm / CSR build ---
    hipMemsetAsync(deg, 0, NNODES * sizeof(int), stream);
    deg_kernel<<<(NEDGES + 255) / 256, 256, 0, stream>>>(dst, deg, NEDGES);
    scan_block<<<NB_SCAN, 256, 0, stream>>>(deg, rowstart, part1, dis, NNODES);
    scan_partials<<<1, 256, 0, stream>>>(part1, part2, NB_SCAN);
    scan_add<<<NB_SCAN, 256, 0, stream>>>(rowstart, part2, cursor, NNODES);
    fill_csr<<<(NEDGES + 255) / 256, 256, 0, stream>>>(src, dst, cursor, csr_src, NEDGES);

    const int ngemm = (NNODES + 127) / 128;

    // --- layer 1: hwh = fp16((x@W1)*dis); h1 -> bufB ---
    gemm_rt<<<ngemm, 256, 0, stream>>>(x, W1, dis, hwh);
    gcn_gather<<<(NNODES * 32) / 256, 256, 0, stream>>>(hwh, rowstart, csr_src, dis, b1, bufB);

    // --- layer 2: hwh = fp16((h1@W2)*dis); h2 -> bufB ---
    gemm_rt<<<ngemm, 256, 0, stream>>>(bufB, W2, dis, hwh);
    gcn_gather<<<(NNODES * 32) / 256, 256, 0, stream>>>(hwh, rowstart, csr_src, dis, b2, bufB);

    // --- fused pooling + head ---
    pool_head<<<NGRAPH, 256, 0, stream>>>(bufB, x, batch, xsrc, Wh, bh, out);
}

// Round 6
// 214.811 us; speedup vs baseline: 14.4310x; 1.1830x over previous
//
#include <hip/hip_runtime.h>
#include <hip/hip_fp16.h>

#define NNODES 50000
#define NEDGES 800000
#define DIM    128
#define NGRAPH 512
#define NB_SCAN 196   // ceil(50000/256)

// ---------- phase 1: per-edge rank via 4-way-unrolled return-atomics; deg as side effect ----------
__global__ void edge_pos(const int4* __restrict__ dst4, int* __restrict__ deg,
                         int4* __restrict__ pos4, int n4) {
    int t = blockIdx.x * blockDim.x + threadIdx.x;
    if (t >= n4) return;
    int4 d = dst4[t];
    int4 p;
    p.x = atomicAdd(&deg[d.x], 1);
    p.y = atomicAdd(&deg[d.y], 1);
    p.z = atomicAdd(&deg[d.z], 1);
    p.w = atomicAdd(&deg[d.w], 1);
    pos4[t] = p;
}

// ---------- exclusive scan (3 kernels); scan_block also emits dis = rsqrt(deg+1) ----------
__global__ void scan_block(const int* __restrict__ in, int* __restrict__ out,
                           int* __restrict__ partials, float* __restrict__ dis, int n) {
    __shared__ int s[256];
    int t = threadIdx.x;
    int gid = blockIdx.x * 256 + t;
    int v = (gid < n) ? in[gid] : 0;
    if (gid < n) dis[gid] = rsqrtf((float)v + 1.0f);
    s[t] = v;
    __syncthreads();
    #pragma unroll
    for (int off = 1; off < 256; off <<= 1) {
        int u = (t >= off) ? s[t - off] : 0;
        __syncthreads();
        s[t] += u;
        __syncthreads();
    }
    if (gid < n) out[gid] = s[t] - v;          // exclusive within block
    if (t == 255) partials[blockIdx.x] = s[255];
}

__global__ void scan_partials(const int* __restrict__ in, int* __restrict__ out, int n) {
    __shared__ int s[256];
    int t = threadIdx.x;
    int v = (t < n) ? in[t] : 0;
    s[t] = v;
    __syncthreads();
    #pragma unroll
    for (int off = 1; off < 256; off <<= 1) {
        int u = (t >= off) ? s[t - off] : 0;
        __syncthreads();
        s[t] += u;
        __syncthreads();
    }
    if (t < n) out[t] = s[t] - v;
}

__global__ void scan_add(int* __restrict__ rowstart, const int* __restrict__ partials2, int n) {
    int gid = blockIdx.x * 256 + threadIdx.x;
    if (gid < n) rowstart[gid] += partials2[blockIdx.x];
    if (gid == 0) rowstart[n] = NEDGES;
}

// ---------- phase 3: atomic-free CSR scatter, 4-way unrolled ----------
__global__ void edge_scatter2(const int4* __restrict__ src4, const int4* __restrict__ dst4,
                              const int4* __restrict__ pos4, const int* __restrict__ rowstart,
                              int* __restrict__ csr_src, int n4) {
    int t = blockIdx.x * blockDim.x + threadIdx.x;
    if (t >= n4) return;
    int4 s = src4[t];
    int4 d = dst4[t];
    int4 p = pos4[t];
    csr_src[rowstart[d.x] + p.x] = s.x;
    csr_src[rowstart[d.y] + p.y] = s.y;
    csr_src[rowstart[d.z] + p.z] = s.z;
    csr_src[rowstart[d.w] + p.w] = s.w;
}

// ---------- register-tiled fp32 GEMM, fp16-packed scaled output ----------
// Yh[n] = fp16((X @ W)[n] * scale[n]).  block=256 -> 128x128 tile, thread 8x8.
#define BK 32
#define XPAD 132
__global__ void __launch_bounds__(256) gemm_rt(const float* __restrict__ X,
                                               const float* __restrict__ W,
                                               const float* __restrict__ scale,
                                               __half* __restrict__ Yh) {
    __shared__ float Xs[BK * XPAD];   // transposed: Xs[k][row], padded
    __shared__ float Ws[BK * DIM];    // Ws[k][n]

    const int t  = threadIdx.x;
    const int tx = t & 15;            // col group (8 cols)
    const int ty = t >> 4;            // row group (8 rows)
    const int bm = blockIdx.x * 128;

    const int lr = t >> 3;            // 0..31
    const int lc = t & 7;             // 0..7

    float acc[8][8];
    #pragma unroll
    for (int i = 0; i < 8; ++i)
        #pragma unroll
        for (int j = 0; j < 8; ++j) acc[i][j] = 0.f;

    for (int k0 = 0; k0 < DIM; k0 += BK) {
        {
            const float4* Wg = (const float4*)(W + (size_t)k0 * DIM);
            float4* Wl = (float4*)Ws;
            #pragma unroll
            for (int i = 0; i < 4; ++i) Wl[t + 256 * i] = Wg[t + 256 * i];
        }
        #pragma unroll
        for (int p = 0; p < 4; ++p) {
            int row = p * 32 + lr;
            int grow = bm + row;
            int crow = grow < NNODES ? grow : NNODES - 1;
            float4 v = *(const float4*)(X + (size_t)crow * DIM + k0 + lc * 4);
            Xs[(lc * 4 + 0) * XPAD + row] = v.x;
            Xs[(lc * 4 + 1) * XPAD + row] = v.y;
            Xs[(lc * 4 + 2) * XPAD + row] = v.z;
            Xs[(lc * 4 + 3) * XPAD + row] = v.w;
        }
        __syncthreads();

        #pragma unroll 4
        for (int kk = 0; kk < BK; ++kk) {
            float4 x0 = *(const float4*)(Xs + kk * XPAD + ty * 8);
            float4 x1 = *(const float4*)(Xs + kk * XPAD + ty * 8 + 4);
            float4 w0 = *(const float4*)(Ws + kk * DIM + tx * 8);
            float4 w1 = *(const float4*)(Ws + kk * DIM + tx * 8 + 4);
            float xv[8] = {x0.x, x0.y, x0.z, x0.w, x1.x, x1.y, x1.z, x1.w};
            float wv[8] = {w0.x, w0.y, w0.z, w0.w, w1.x, w1.y, w1.z, w1.w};
            #pragma unroll
            for (int i = 0; i < 8; ++i)
                #pragma unroll
                for (int j = 0; j < 8; ++j)
                    acc[i][j] = fmaf(xv[i], wv[j], acc[i][j]);
        }
        __syncthreads();
    }

    #pragma unroll
    for (int i = 0; i < 8; ++i) {
        int grow = bm + ty * 8 + i;
        if (grow < NNODES) {
            float s = scale[grow];
            __half2 p0 = __floats2half2_rn(acc[i][0] * s, acc[i][1] * s);
            __half2 p1 = __floats2half2_rn(acc[i][2] * s, acc[i][3] * s);
            __half2 p2 = __floats2half2_rn(acc[i][4] * s, acc[i][5] * s);
            __half2 p3 = __floats2half2_rn(acc[i][6] * s, acc[i][7] * s);
            uint4 pk;
            pk.x = *(unsigned*)&p0; pk.y = *(unsigned*)&p1;
            pk.z = *(unsigned*)&p2; pk.w = *(unsigned*)&p3;
            *(uint4*)(Yh + (size_t)grow * DIM + tx * 8) = pk;
        }
    }
}

// ---------- GCN aggregate: fp16 gather-sum, fp32 accumulate ----------
// out[d] = relu(dis[d] * (sum_{s in N(d)} hw'[s] + hw'[d]) + b)
__device__ __forceinline__ void acc_add(float4& a, uint2 u) {
    float2 f0 = __half22float2(*(__half2*)&u.x);
    float2 f1 = __half22float2(*(__half2*)&u.y);
    a.x += f0.x; a.y += f0.y; a.z += f1.x; a.w += f1.y;
}

__global__ void __launch_bounds__(256) gcn_gather(const __half* __restrict__ hwh,
                                                  const int* __restrict__ rowstart,
                                                  const int* __restrict__ csr_src,
                                                  const float* __restrict__ dis,
                                                  const float* __restrict__ b,
                                                  float* __restrict__ out) {
    int t = blockIdx.x * 256 + threadIdx.x;
    int d = t >> 5, q = t & 31;
    if (d >= NNODES) return;
    const uint2* hw8 = (const uint2*)hwh;   // 32 uint2 per 128-half row

    float4 a0 = make_float4(0.f, 0.f, 0.f, 0.f);
    float4 a1 = make_float4(0.f, 0.f, 0.f, 0.f);
    float4 a2 = make_float4(0.f, 0.f, 0.f, 0.f);
    float4 a3 = make_float4(0.f, 0.f, 0.f, 0.f);
    float4 a4 = make_float4(0.f, 0.f, 0.f, 0.f);
    float4 a5 = make_float4(0.f, 0.f, 0.f, 0.f);
    float4 a6 = make_float4(0.f, 0.f, 0.f, 0.f);
    float4 a7 = make_float4(0.f, 0.f, 0.f, 0.f);

    acc_add(a0, hw8[(size_t)d * 32 + q]);   // self-loop (pre-scaled)

    int beg = rowstart[d], end = rowstart[d + 1];
    int i = beg;
    for (; i + 8 <= end; i += 8) {
        int s0 = csr_src[i + 0], s1 = csr_src[i + 1];
        int s2 = csr_src[i + 2], s3 = csr_src[i + 3];
        int s4 = csr_src[i + 4], s5 = csr_src[i + 5];
        int s6 = csr_src[i + 6], s7 = csr_src[i + 7];
        uint2 v0 = hw8[(size_t)s0 * 32 + q];
        uint2 v1 = hw8[(size_t)s1 * 32 + q];
        uint2 v2 = hw8[(size_t)s2 * 32 + q];
        uint2 v3 = hw8[(size_t)s3 * 32 + q];
        uint2 v4 = hw8[(size_t)s4 * 32 + q];
        uint2 v5 = hw8[(size_t)s5 * 32 + q];
        uint2 v6 = hw8[(size_t)s6 * 32 + q];
        uint2 v7 = hw8[(size_t)s7 * 32 + q];
        acc_add(a0, v0); acc_add(a1, v1); acc_add(a2, v2); acc_add(a3, v3);
        acc_add(a4, v4); acc_add(a5, v5); acc_add(a6, v6); acc_add(a7, v7);
    }
    for (; i + 2 <= end; i += 2) {
        uint2 v0 = hw8[(size_t)csr_src[i + 0] * 32 + q];
        uint2 v1 = hw8[(size_t)csr_src[i + 1] * 32 + q];
        acc_add(a0, v0); acc_add(a1, v1);
    }
    if (i < end) acc_add(a0, hw8[(size_t)csr_src[i] * 32 + q]);

    a0.x += a1.x + a2.x + a3.x + a4.x + a5.x + a6.x + a7.x;
    a0.y += a1.y + a2.y + a3.y + a4.y + a5.y + a6.y + a7.y;
    a0.z += a1.z + a2.z + a3.z + a4.z + a5.z + a6.z + a7.z;
    a0.w += a1.w + a2.w + a3.w + a4.w + a5.w + a6.w + a7.w;

    float dd = dis[d];
    float4 bb = ((const float4*)b)[q];
    a0.x = fmaxf(fmaf(a0.x, dd, bb.x), 0.f);
    a0.y = fmaxf(fmaf(a0.y, dd, bb.y), 0.f);
    a0.z = fmaxf(fmaf(a0.z, dd, bb.z), 0.f);
    a0.w = fmaxf(fmaf(a0.w, dd, bb.w), 0.f);
    ((float4*)out)[(size_t)d * 32 + q] = a0;
}

// ---------- fused pooling + head: one 256-thread block per graph ----------
__device__ __forceinline__ int lower_bound_i(const int* __restrict__ a, int n, int v) {
    int lo = 0, hi = n;
    while (lo < hi) {
        int mid = (lo + hi) >> 1;
        if (a[mid] < v) lo = mid + 1; else hi = mid;
    }
    return lo;
}

__global__ void __launch_bounds__(256) pool_head(const float* __restrict__ h,
                                                 const float* __restrict__ x,
                                                 const int* __restrict__ batch,
                                                 const int* __restrict__ xsrc,
                                                 const float* __restrict__ Wh,
                                                 const float* __restrict__ bh,
                                                 float* __restrict__ out) {
    __shared__ float sAG[DIM];
    __shared__ float sAC[DIM];
    __shared__ int   sSC;
    int g   = blockIdx.x;
    int t   = threadIdx.x;
    int sub = t >> 5;      // 0..7 parallel row chains
    int q   = t & 31;

    if (t < DIM) { sAG[t] = 0.f; sAC[t] = 0.f; }
    if (t == 0) sSC = 0;
    __syncthreads();

    int lo = lower_bound_i(batch, NNODES, g);
    int hi = lower_bound_i(batch, NNODES, g + 1);

    float4 ag = make_float4(0.f, 0.f, 0.f, 0.f);
    float4 ac = make_float4(0.f, 0.f, 0.f, 0.f);
    int sc = 0;
    const float4* h4 = (const float4*)h;
    const float4* x4 = (const float4*)x;
    for (int r = lo + sub; r < hi; r += 8) {
        float4 hv = h4[(size_t)r * 32 + q];
        ag.x += hv.x; ag.y += hv.y; ag.z += hv.z; ag.w += hv.w;
        if (xsrc[r] == 1) {
            float4 xv = x4[(size_t)r * 32 + q];
            ac.x += xv.x; ac.y += xv.y; ac.z += xv.z; ac.w += xv.w;
            sc++;
        }
    }
    float* agp = sAG + q * 4;
    atomicAdd(agp + 0, ag.x); atomicAdd(agp + 1, ag.y);
    atomicAdd(agp + 2, ag.z); atomicAdd(agp + 3, ag.w);
    float* acp = sAC + q * 4;
    atomicAdd(acp + 0, ac.x); atomicAdd(acp + 1, ac.y);
    atomicAdd(acp + 2, ac.z); atomicAdd(acp + 3, ac.w);
    if (q == 0 && sc) atomicAdd(&sSC, sc);
    __syncthreads();

    if (t < 32) {
        float invg = 1.0f / fmaxf((float)(hi - lo), 1.0f);
        float invc = 1.0f / fmaxf((float)sSC, 1.0f);
        const float2* Wh2 = (const float2*)Wh;
        float a0 = 0.f, a1 = 0.f;
        #pragma unroll
        for (int j = 0; j < 4; ++j) {
            float e1 = sAG[t * 4 + j] * invg;
            float2 w1 = Wh2[t * 4 + j];
            a0 = fmaf(e1, w1.x, a0);
            a1 = fmaf(e1, w1.y, a1);
            float e2 = sAC[t * 4 + j] * invc;
            float2 w2 = Wh2[DIM + t * 4 + j];
            a0 = fmaf(e2, w2.x, a0);
            a1 = fmaf(e2, w2.y, a1);
        }
        #pragma unroll
        for (int off = 16; off; off >>= 1) {
            a0 += __shfl_down(a0, off, 32);
            a1 += __shfl_down(a1, off, 32);
        }
        if (t == 0) {
            out[g * 2 + 0] = a0 + bh[0];
            out[g * 2 + 1] = a1 + bh[1];
        }
    }
}

extern "C" void kernel_launch(void* const* d_in, const int* in_sizes, int n_in,
                              void* d_out, int out_size, void* d_ws, size_t ws_size,
                              hipStream_t stream) {
    const float* x     = (const float*)d_in[0];
    const int*   ei    = (const int*)d_in[1];       // [2, E] int32
    const int*   batch = (const int*)d_in[2];
    const int*   xsrc  = (const int*)d_in[3];
    const float* W1 = (const float*)d_in[4];
    const float* b1 = (const float*)d_in[5];
    const float* W2 = (const float*)d_in[6];
    const float* b2 = (const float*)d_in[7];
    const float* Wh = (const float*)d_in[8];
    const float* bh = (const float*)d_in[9];
    float* out = (float*)d_out;

    const int* src = ei;
    const int* dst = ei + NEDGES;

    // workspace layout (4-byte units)
    float* ws = (float*)d_ws;
    size_t off = 0;
    float*  dis      = ws + off;         off += 50048;
    int*    rowstart = (int*)(ws + off); off += 50048;   // need 50001
    int*    deg      = (int*)(ws + off); off += 50048;
    int*    part1    = (int*)(ws + off); off += 256;
    int*    part2    = (int*)(ws + off); off += 256;
    int*    pos      = (int*)(ws + off); off += 800000;
    int*    csr_src  = (int*)(ws + off); off += 800000;
    __half* hwh      = (__half*)(ws + off); off += (size_t)NNODES * DIM / 2;
    float*  bufB     = ws + off;         off += (size_t)NNODES * DIM;

    const int n4 = NEDGES / 4;   // 200000

    // --- CSR build: rank-atomics -> scan -> atomic-free scatter ---
    hipMemsetAsync(deg, 0, NNODES * sizeof(int), stream);
    edge_pos<<<(n4 + 255) / 256, 256, 0, stream>>>((const int4*)dst, deg, (int4*)pos, n4);
    scan_block<<<NB_SCAN, 256, 0, stream>>>(deg, rowstart, part1, dis, NNODES);
    scan_partials<<<1, 256, 0, stream>>>(part1, part2, NB_SCAN);
    scan_add<<<NB_SCAN, 256, 0, stream>>>(rowstart, part2, NNODES);
    edge_scatter2<<<(n4 + 255) / 256, 256, 0, stream>>>((const int4*)src, (const int4*)dst,
                                                        (const int4*)pos, rowstart, csr_src, n4);

    const int ngemm = (NNODES + 127) / 128;

    // --- layer 1: hwh = fp16((x@W1)*dis); h1 -> bufB ---
    gemm_rt<<<ngemm, 256, 0, stream>>>(x, W1, dis, hwh);
    gcn_gather<<<(NNODES * 32) / 256, 256, 0, stream>>>(hwh, rowstart, csr_src, dis, b1, bufB);

    // --- layer 2: hwh = fp16((h1@W2)*dis); h2 -> bufB ---
    gemm_rt<<<ngemm, 256, 0, stream>>>(bufB, W2, dis, hwh);
    gcn_gather<<<(NNODES * 32) / 256, 256, 0, stream>>>(hwh, rowstart, csr_src, dis, b2, bufB);

    // --- fused pooling + head ---
    pool_head<<<NGRAPH, 256, 0, stream>>>(bufB, x, batch, xsrc, Wh, bh, out);
}

// Round 7
// 213.388 us; speedup vs baseline: 14.5273x; 1.0067x over previous
//
#include <hip/hip_runtime.h>
#include <hip/hip_fp16.h>

#define NNODES 50000
#define NEDGES 800000
#define DIM    128
#define NGRAPH 512
#define NB_SCAN 196   // ceil(50000/256)

// ---------- zero the degree array (replaces 40us runtime fill) ----------
__global__ void zero_deg(int4* __restrict__ deg4) {
    int t = blockIdx.x * 256 + threadIdx.x;
    if (t < NNODES / 4) deg4[t] = make_int4(0, 0, 0, 0);
}

// ---------- phase 1: per-edge rank via 8-way-unrolled return-atomics; deg as side effect ----------
__global__ void edge_pos(const int4* __restrict__ dst4, int* __restrict__ deg,
                         int4* __restrict__ pos4, int n8) {
    int t = blockIdx.x * blockDim.x + threadIdx.x;
    if (t >= n8) return;
    int4 d0 = dst4[t * 2 + 0];
    int4 d1 = dst4[t * 2 + 1];
    int4 p0, p1;
    p0.x = atomicAdd(&deg[d0.x], 1);
    p0.y = atomicAdd(&deg[d0.y], 1);
    p0.z = atomicAdd(&deg[d0.z], 1);
    p0.w = atomicAdd(&deg[d0.w], 1);
    p1.x = atomicAdd(&deg[d1.x], 1);
    p1.y = atomicAdd(&deg[d1.y], 1);
    p1.z = atomicAdd(&deg[d1.z], 1);
    p1.w = atomicAdd(&deg[d1.w], 1);
    pos4[t * 2 + 0] = p0;
    pos4[t * 2 + 1] = p1;
}

// ---------- exclusive scan (3 kernels); scan_block also emits dis = rsqrt(deg+1) ----------
__global__ void scan_block(const int* __restrict__ in, int* __restrict__ out,
                           int* __restrict__ partials, float* __restrict__ dis, int n) {
    __shared__ int s[256];
    int t = threadIdx.x;
    int gid = blockIdx.x * 256 + t;
    int v = (gid < n) ? in[gid] : 0;
    if (gid < n) dis[gid] = rsqrtf((float)v + 1.0f);
    s[t] = v;
    __syncthreads();
    #pragma unroll
    for (int off = 1; off < 256; off <<= 1) {
        int u = (t >= off) ? s[t - off] : 0;
        __syncthreads();
        s[t] += u;
        __syncthreads();
    }
    if (gid < n) out[gid] = s[t] - v;          // exclusive within block
    if (t == 255) partials[blockIdx.x] = s[255];
}

__global__ void scan_partials(const int* __restrict__ in, int* __restrict__ out, int n) {
    __shared__ int s[256];
    int t = threadIdx.x;
    int v = (t < n) ? in[t] : 0;
    s[t] = v;
    __syncthreads();
    #pragma unroll
    for (int off = 1; off < 256; off <<= 1) {
        int u = (t >= off) ? s[t - off] : 0;
        __syncthreads();
        s[t] += u;
        __syncthreads();
    }
    if (t < n) out[t] = s[t] - v;
}

__global__ void scan_add(int* __restrict__ rowstart, const int* __restrict__ partials2, int n) {
    int gid = blockIdx.x * 256 + threadIdx.x;
    if (gid < n) rowstart[gid] += partials2[blockIdx.x];
    if (gid == 0) rowstart[n] = NEDGES;
}

// ---------- phase 3: atomic-free CSR scatter, 4-way unrolled ----------
__global__ void edge_scatter2(const int4* __restrict__ src4, const int4* __restrict__ dst4,
                              const int4* __restrict__ pos4, const int* __restrict__ rowstart,
                              int* __restrict__ csr_src, int n4) {
    int t = blockIdx.x * blockDim.x + threadIdx.x;
    if (t >= n4) return;
    int4 s = src4[t];
    int4 d = dst4[t];
    int4 p = pos4[t];
    csr_src[rowstart[d.x] + p.x] = s.x;
    csr_src[rowstart[d.y] + p.y] = s.y;
    csr_src[rowstart[d.z] + p.z] = s.z;
    csr_src[rowstart[d.w] + p.w] = s.w;
}

// ---------- register-tiled fp32 GEMM, fp16-packed scaled output ----------
// Yh[n] = fp16((X @ W)[n] * scale[n]).  block=256 -> 128x128 tile, thread 8x8.
#define BK 32
#define XPAD 132
__global__ void __launch_bounds__(256) gemm_rt(const float* __restrict__ X,
                                               const float* __restrict__ W,
                                               const float* __restrict__ scale,
                                               __half* __restrict__ Yh) {
    __shared__ float Xs[BK * XPAD];   // transposed: Xs[k][row], padded
    __shared__ float Ws[BK * DIM];    // Ws[k][n]

    const int t  = threadIdx.x;
    const int tx = t & 15;            // col group (8 cols)
    const int ty = t >> 4;            // row group (8 rows)
    const int bm = blockIdx.x * 128;

    const int lr = t >> 3;            // 0..31
    const int lc = t & 7;             // 0..7

    float acc[8][8];
    #pragma unroll
    for (int i = 0; i < 8; ++i)
        #pragma unroll
        for (int j = 0; j < 8; ++j) acc[i][j] = 0.f;

    for (int k0 = 0; k0 < DIM; k0 += BK) {
        {
            const float4* Wg = (const float4*)(W + (size_t)k0 * DIM);
            float4* Wl = (float4*)Ws;
            #pragma unroll
            for (int i = 0; i < 4; ++i) Wl[t + 256 * i] = Wg[t + 256 * i];
        }
        #pragma unroll
        for (int p = 0; p < 4; ++p) {
            int row = p * 32 + lr;
            int grow = bm + row;
            int crow = grow < NNODES ? grow : NNODES - 1;
            float4 v = *(const float4*)(X + (size_t)crow * DIM + k0 + lc * 4);
            Xs[(lc * 4 + 0) * XPAD + row] = v.x;
            Xs[(lc * 4 + 1) * XPAD + row] = v.y;
            Xs[(lc * 4 + 2) * XPAD + row] = v.z;
            Xs[(lc * 4 + 3) * XPAD + row] = v.w;
        }
        __syncthreads();

        #pragma unroll 4
        for (int kk = 0; kk < BK; ++kk) {
            float4 x0 = *(const float4*)(Xs + kk * XPAD + ty * 8);
            float4 x1 = *(const float4*)(Xs + kk * XPAD + ty * 8 + 4);
            float4 w0 = *(const float4*)(Ws + kk * DIM + tx * 8);
            float4 w1 = *(const float4*)(Ws + kk * DIM + tx * 8 + 4);
            float xv[8] = {x0.x, x0.y, x0.z, x0.w, x1.x, x1.y, x1.z, x1.w};
            float wv[8] = {w0.x, w0.y, w0.z, w0.w, w1.x, w1.y, w1.z, w1.w};
            #pragma unroll
            for (int i = 0; i < 8; ++i)
                #pragma unroll
                for (int j = 0; j < 8; ++j)
                    acc[i][j] = fmaf(xv[i], wv[j], acc[i][j]);
        }
        __syncthreads();
    }

    #pragma unroll
    for (int i = 0; i < 8; ++i) {
        int grow = bm + ty * 8 + i;
        if (grow < NNODES) {
            float s = scale[grow];
            __half2 p0 = __floats2half2_rn(acc[i][0] * s, acc[i][1] * s);
            __half2 p1 = __floats2half2_rn(acc[i][2] * s, acc[i][3] * s);
            __half2 p2 = __floats2half2_rn(acc[i][4] * s, acc[i][5] * s);
            __half2 p3 = __floats2half2_rn(acc[i][6] * s, acc[i][7] * s);
            uint4 pk;
            pk.x = *(unsigned*)&p0; pk.y = *(unsigned*)&p1;
            pk.z = *(unsigned*)&p2; pk.w = *(unsigned*)&p3;
            *(uint4*)(Yh + (size_t)grow * DIM + tx * 8) = pk;
        }
    }
}

// ---------- GCN aggregate: fp16 gather-sum, fp32 accumulate ----------
// out[d] = relu(dis[d] * (sum_{s in N(d)} hw'[s] + hw'[d]) + b)
__device__ __forceinline__ void acc_add(float4& a, uint2 u) {
    float2 f0 = __half22float2(*(__half2*)&u.x);
    float2 f1 = __half22float2(*(__half2*)&u.y);
    a.x += f0.x; a.y += f0.y; a.z += f1.x; a.w += f1.y;
}

__global__ void __launch_bounds__(256) gcn_gather(const __half* __restrict__ hwh,
                                                  const int* __restrict__ rowstart,
                                                  const int* __restrict__ csr_src,
                                                  const float* __restrict__ dis,
                                                  const float* __restrict__ b,
                                                  float* __restrict__ out) {
    int t = blockIdx.x * 256 + threadIdx.x;
    int d = t >> 5, q = t & 31;
    if (d >= NNODES) return;
    const uint2* hw8 = (const uint2*)hwh;   // 32 uint2 per 128-half row

    float4 a0 = make_float4(0.f, 0.f, 0.f, 0.f);
    float4 a1 = make_float4(0.f, 0.f, 0.f, 0.f);
    float4 a2 = make_float4(0.f, 0.f, 0.f, 0.f);
    float4 a3 = make_float4(0.f, 0.f, 0.f, 0.f);
    float4 a4 = make_float4(0.f, 0.f, 0.f, 0.f);
    float4 a5 = make_float4(0.f, 0.f, 0.f, 0.f);
    float4 a6 = make_float4(0.f, 0.f, 0.f, 0.f);
    float4 a7 = make_float4(0.f, 0.f, 0.f, 0.f);

    acc_add(a0, hw8[(size_t)d * 32 + q]);   // self-loop (pre-scaled)

    int beg = rowstart[d], end = rowstart[d + 1];
    int i = beg;
    for (; i + 8 <= end; i += 8) {
        int s0 = csr_src[i + 0], s1 = csr_src[i + 1];
        int s2 = csr_src[i + 2], s3 = csr_src[i + 3];
        int s4 = csr_src[i + 4], s5 = csr_src[i + 5];
        int s6 = csr_src[i + 6], s7 = csr_src[i + 7];
        uint2 v0 = hw8[(size_t)s0 * 32 + q];
        uint2 v1 = hw8[(size_t)s1 * 32 + q];
        uint2 v2 = hw8[(size_t)s2 * 32 + q];
        uint2 v3 = hw8[(size_t)s3 * 32 + q];
        uint2 v4 = hw8[(size_t)s4 * 32 + q];
        uint2 v5 = hw8[(size_t)s5 * 32 + q];
        uint2 v6 = hw8[(size_t)s6 * 32 + q];
        uint2 v7 = hw8[(size_t)s7 * 32 + q];
        acc_add(a0, v0); acc_add(a1, v1); acc_add(a2, v2); acc_add(a3, v3);
        acc_add(a4, v4); acc_add(a5, v5); acc_add(a6, v6); acc_add(a7, v7);
    }
    for (; i + 2 <= end; i += 2) {
        uint2 v0 = hw8[(size_t)csr_src[i + 0] * 32 + q];
        uint2 v1 = hw8[(size_t)csr_src[i + 1] * 32 + q];
        acc_add(a0, v0); acc_add(a1, v1);
    }
    if (i < end) acc_add(a0, hw8[(size_t)csr_src[i] * 32 + q]);

    a0.x += a1.x + a2.x + a3.x + a4.x + a5.x + a6.x + a7.x;
    a0.y += a1.y + a2.y + a3.y + a4.y + a5.y + a6.y + a7.y;
    a0.z += a1.z + a2.z + a3.z + a4.z + a5.z + a6.z + a7.z;
    a0.w += a1.w + a2.w + a3.w + a4.w + a5.w + a6.w + a7.w;

    float dd = dis[d];
    float4 bb = ((const float4*)b)[q];
    a0.x = fmaxf(fmaf(a0.x, dd, bb.x), 0.f);
    a0.y = fmaxf(fmaf(a0.y, dd, bb.y), 0.f);
    a0.z = fmaxf(fmaf(a0.z, dd, bb.z), 0.f);
    a0.w = fmaxf(fmaf(a0.w, dd, bb.w), 0.f);
    ((float4*)out)[(size_t)d * 32 + q] = a0;
}

// ---------- fused pooling + head: one 256-thread block per graph ----------
__device__ __forceinline__ int lower_bound_i(const int* __restrict__ a, int n, int v) {
    int lo = 0, hi = n;
    while (lo < hi) {
        int mid = (lo + hi) >> 1;
        if (a[mid] < v) lo = mid + 1; else hi = mid;
    }
    return lo;
}

__global__ void __launch_bounds__(256) pool_head(const float* __restrict__ h,
                                                 const float* __restrict__ x,
                                                 const int* __restrict__ batch,
                                                 const int* __restrict__ xsrc,
                                                 const float* __restrict__ Wh,
                                                 const float* __restrict__ bh,
                                                 float* __restrict__ out) {
    __shared__ float sAG[DIM];
    __shared__ float sAC[DIM];
    __shared__ int   sSC;
    int g   = blockIdx.x;
    int t   = threadIdx.x;
    int sub = t >> 5;      // 0..7 parallel row chains
    int q   = t & 31;

    if (t < DIM) { sAG[t] = 0.f; sAC[t] = 0.f; }
    if (t == 0) sSC = 0;
    __syncthreads();

    int lo = lower_bound_i(batch, NNODES, g);
    int hi = lower_bound_i(batch, NNODES, g + 1);

    float4 ag = make_float4(0.f, 0.f, 0.f, 0.f);
    float4 ac = make_float4(0.f, 0.f, 0.f, 0.f);
    int sc = 0;
    const float4* h4 = (const float4*)h;
    const float4* x4 = (const float4*)x;
    for (int r = lo + sub; r < hi; r += 8) {
        float4 hv = h4[(size_t)r * 32 + q];
        ag.x += hv.x; ag.y += hv.y; ag.z += hv.z; ag.w += hv.w;
        if (xsrc[r] == 1) {
            float4 xv = x4[(size_t)r * 32 + q];
            ac.x += xv.x; ac.y += xv.y; ac.z += xv.z; ac.w += xv.w;
            sc++;
        }
    }
    float* agp = sAG + q * 4;
    atomicAdd(agp + 0, ag.x); atomicAdd(agp + 1, ag.y);
    atomicAdd(agp + 2, ag.z); atomicAdd(agp + 3, ag.w);
    float* acp = sAC + q * 4;
    atomicAdd(acp + 0, ac.x); atomicAdd(acp + 1, ac.y);
    atomicAdd(acp + 2, ac.z); atomicAdd(acp + 3, ac.w);
    if (q == 0 && sc) atomicAdd(&sSC, sc);
    __syncthreads();

    if (t < 32) {
        float invg = 1.0f / fmaxf((float)(hi - lo), 1.0f);
        float invc = 1.0f / fmaxf((float)sSC, 1.0f);
        const float2* Wh2 = (const float2*)Wh;
        float a0 = 0.f, a1 = 0.f;
        #pragma unroll
        for (int j = 0; j < 4; ++j) {
            float e1 = sAG[t * 4 + j] * invg;
            float2 w1 = Wh2[t * 4 + j];
            a0 = fmaf(e1, w1.x, a0);
            a1 = fmaf(e1, w1.y, a1);
            float e2 = sAC[t * 4 + j] * invc;
            float2 w2 = Wh2[DIM + t * 4 + j];
            a0 = fmaf(e2, w2.x, a0);
            a1 = fmaf(e2, w2.y, a1);
        }
        #pragma unroll
        for (int off = 16; off; off >>= 1) {
            a0 += __shfl_down(a0, off, 32);
            a1 += __shfl_down(a1, off, 32);
        }
        if (t == 0) {
            out[g * 2 + 0] = a0 + bh[0];
            out[g * 2 + 1] = a1 + bh[1];
        }
    }
}

extern "C" void kernel_launch(void* const* d_in, const int* in_sizes, int n_in,
                              void* d_out, int out_size, void* d_ws, size_t ws_size,
                              hipStream_t stream) {
    const float* x     = (const float*)d_in[0];
    const int*   ei    = (const int*)d_in[1];       // [2, E] int32
    const int*   batch = (const int*)d_in[2];
    const int*   xsrc  = (const int*)d_in[3];
    const float* W1 = (const float*)d_in[4];
    const float* b1 = (const float*)d_in[5];
    const float* W2 = (const float*)d_in[6];
    const float* b2 = (const float*)d_in[7];
    const float* Wh = (const float*)d_in[8];
    const float* bh = (const float*)d_in[9];
    float* out = (float*)d_out;

    const int* src = ei;
    const int* dst = ei + NEDGES;

    // workspace layout (4-byte units)
    float* ws = (float*)d_ws;
    size_t off = 0;
    float*  dis      = ws + off;         off += 50048;
    int*    rowstart = (int*)(ws + off); off += 50048;   // need 50001
    int*    deg      = (int*)(ws + off); off += 50048;
    int*    part1    = (int*)(ws + off); off += 256;
    int*    part2    = (int*)(ws + off); off += 256;
    int*    pos      = (int*)(ws + off); off += 800000;
    int*    csr_src  = (int*)(ws + off); off += 800000;
    __half* hwh      = (__half*)(ws + off); off += (size_t)NNODES * DIM / 2;
    float*  bufB     = ws + off;         off += (size_t)NNODES * DIM;

    const int n4 = NEDGES / 4;   // 200000
    const int n8 = NEDGES / 8;   // 100000

    // --- CSR build: zero -> rank-atomics -> scan -> atomic-free scatter ---
    zero_deg<<<(NNODES / 4 + 255) / 256, 256, 0, stream>>>((int4*)deg);
    edge_pos<<<(n8 + 255) / 256, 256, 0, stream>>>((const int4*)dst, deg, (int4*)pos, n8);
    scan_block<<<NB_SCAN, 256, 0, stream>>>(deg, rowstart, part1, dis, NNODES);
    scan_partials<<<1, 256, 0, stream>>>(part1, part2, NB_SCAN);
    scan_add<<<NB_SCAN, 256, 0, stream>>>(rowstart, part2, NNODES);
    edge_scatter2<<<(n4 + 255) / 256, 256, 0, stream>>>((const int4*)src, (const int4*)dst,
                                                        (const int4*)pos, rowstart, csr_src, n4);

    const int ngemm = (NNODES + 127) / 128;

    // --- layer 1: hwh = fp16((x@W1)*dis); h1 -> bufB ---
    gemm_rt<<<ngemm, 256, 0, stream>>>(x, W1, dis, hwh);
    gcn_gather<<<(NNODES * 32) / 256, 256, 0, stream>>>(hwh, rowstart, csr_src, dis, b1, bufB);

    // --- layer 2: hwh = fp16((h1@W2)*dis); h2 -> bufB ---
    gemm_rt<<<ngemm, 256, 0, stream>>>(bufB, W2, dis, hwh);
    gcn_gather<<<(NNODES * 32) / 256, 256, 0, stream>>>(hwh, rowstart, csr_src, dis, b2, bufB);

    // --- fused pooling + head ---
    pool_head<<<NGRAPH, 256, 0, stream>>>(bufB, x, batch, xsrc, Wh, bh, out);
}

// Round 8
// 176.400 us; speedup vs baseline: 17.5733x; 1.2097x over previous
//
#include <hip/hip_runtime.h>
#include <hip/hip_fp16.h>

#define NNODES 50000
#define NEDGES 800000
#define DIM    128
#define NGRAPH 512
#define NB_SCAN 196   // ceil(50000/256)
#define NSLAB  3125   // 50000/16

typedef _Float16 f16x8 __attribute__((ext_vector_type(8)));
typedef float    f32x4 __attribute__((ext_vector_type(4)));
union U4H8 { uint4 u; f16x8 h; };

// ---------- prep: zero degree array + transpose W1/W2 to fp16 Wt[col][k] ----------
__global__ void prep(int4* __restrict__ deg4,
                     const float* __restrict__ W1, const float* __restrict__ W2,
                     __half* __restrict__ Wt1, __half* __restrict__ Wt2) {
    int t = blockIdx.x * 256 + threadIdx.x;
    if (t < NNODES / 4) { deg4[t] = make_int4(0, 0, 0, 0); return; }
    int i = t - NNODES / 4;
    if (i >= 4096) return;
    const float* W = (i < 2048) ? W1 : W2;
    __half* Wt = (i < 2048) ? Wt1 : Wt2;
    int j = i & 2047;
    int c  = j >> 4;          // output row = original col, 0..127
    int k0 = (j & 15) * 8;    // 8 k's per thread
    __half tmp[8];
    #pragma unroll
    for (int u = 0; u < 8; ++u) tmp[u] = (__half)W[(size_t)(k0 + u) * DIM + c];
    *(uint4*)(Wt + (size_t)c * DIM + k0) = *(uint4*)tmp;
}

// ---------- per-edge rank via 8-way-unrolled return-atomics; deg as side effect ----------
__global__ void edge_pos(const int4* __restrict__ dst4, int* __restrict__ deg,
                         int4* __restrict__ pos4, int n8) {
    int t = blockIdx.x * blockDim.x + threadIdx.x;
    if (t >= n8) return;
    int4 d0 = dst4[t * 2 + 0];
    int4 d1 = dst4[t * 2 + 1];
    int4 p0, p1;
    p0.x = atomicAdd(&deg[d0.x], 1);
    p0.y = atomicAdd(&deg[d0.y], 1);
    p0.z = atomicAdd(&deg[d0.z], 1);
    p0.w = atomicAdd(&deg[d0.w], 1);
    p1.x = atomicAdd(&deg[d1.x], 1);
    p1.y = atomicAdd(&deg[d1.y], 1);
    p1.z = atomicAdd(&deg[d1.z], 1);
    p1.w = atomicAdd(&deg[d1.w], 1);
    pos4[t * 2 + 0] = p0;
    pos4[t * 2 + 1] = p1;
}

// ---------- exclusive scan (3 kernels); scan_block also emits dis = rsqrt(deg+1) ----------
__global__ void scan_block(const int* __restrict__ in, int* __restrict__ out,
                           int* __restrict__ partials, float* __restrict__ dis, int n) {
    __shared__ int s[256];
    int t = threadIdx.x;
    int gid = blockIdx.x * 256 + t;
    int v = (gid < n) ? in[gid] : 0;
    if (gid < n) dis[gid] = rsqrtf((float)v + 1.0f);
    s[t] = v;
    __syncthreads();
    #pragma unroll
    for (int off = 1; off < 256; off <<= 1) {
        int u = (t >= off) ? s[t - off] : 0;
        __syncthreads();
        s[t] += u;
        __syncthreads();
    }
    if (gid < n) out[gid] = s[t] - v;
    if (t == 255) partials[blockIdx.x] = s[255];
}

__global__ void scan_partials(const int* __restrict__ in, int* __restrict__ out, int n) {
    __shared__ int s[256];
    int t = threadIdx.x;
    int v = (t < n) ? in[t] : 0;
    s[t] = v;
    __syncthreads();
    #pragma unroll
    for (int off = 1; off < 256; off <<= 1) {
        int u = (t >= off) ? s[t - off] : 0;
        __syncthreads();
        s[t] += u;
        __syncthreads();
    }
    if (t < n) out[t] = s[t] - v;
}

__global__ void scan_add(int* __restrict__ rowstart, const int* __restrict__ partials2, int n) {
    int gid = blockIdx.x * 256 + threadIdx.x;
    if (gid < n) rowstart[gid] += partials2[blockIdx.x];
    if (gid == 0) rowstart[n] = NEDGES;
}

// ---------- atomic-free CSR scatter, 4-way unrolled ----------
__global__ void edge_scatter2(const int4* __restrict__ src4, const int4* __restrict__ dst4,
                              const int4* __restrict__ pos4, const int* __restrict__ rowstart,
                              int* __restrict__ csr_src, int n4) {
    int t = blockIdx.x * blockDim.x + threadIdx.x;
    if (t >= n4) return;
    int4 s = src4[t];
    int4 d = dst4[t];
    int4 p = pos4[t];
    csr_src[rowstart[d.x] + p.x] = s.x;
    csr_src[rowstart[d.y] + p.y] = s.y;
    csr_src[rowstart[d.z] + p.z] = s.z;
    csr_src[rowstart[d.w] + p.w] = s.w;
}

// ---------- MFMA fp16 GEMM: Yh[row] = fp16((X @ W)[row] * dis[row]) ----------
// 256 threads = 4 waves; each wave computes a 16-row x 128-col slab via
// mfma_f32_16x16x32_f16 (A row=lane&15, k=8*(lane>>4)+j; B col=lane&15, same k;
// D col=lane&15, row=4*(lane>>4)+reg — m89-verified mapping).
template<typename XT>
__global__ void __launch_bounds__(256) gemm_mfma(const XT* __restrict__ X,
                                                 const __half* __restrict__ Wt,  // [128][128] fp16, Wt[col][k]
                                                 const float* __restrict__ dis,
                                                 __half* __restrict__ Y) {
    __shared__ __align__(16) unsigned char Wl[128 * 256];   // 32KB, XOR-swizzled rows

    const int t = threadIdx.x;
    // stage Wt -> LDS, swizzle: byte_off_in_row ^= (col&7)<<4
    {
        int col = t >> 1;
        int kb0 = (t & 1) * 128;
        const unsigned char* g = (const unsigned char*)Wt + col * 256 + kb0;
        #pragma unroll
        for (int i = 0; i < 8; ++i) {
            uint4 v = *(const uint4*)(g + i * 16);
            int kb = kb0 + i * 16;
            *(uint4*)(Wl + col * 256 + (kb ^ ((col & 7) << 4))) = v;
        }
    }
    __syncthreads();

    int wave = t >> 6;
    int slab = blockIdx.x * 4 + wave;
    if (slab >= NSLAB) return;
    int l  = t & 63;
    int lr = l & 15;        // A row within slab / D col
    int lg = l >> 4;        // k-group / D row-group

    int arow = slab * 16 + lr;

    f16x8 afr[4];
    if constexpr (sizeof(XT) == 4) {
        const float* xr = (const float*)X + (size_t)arow * DIM;
        #pragma unroll
        for (int c = 0; c < 4; ++c) {
            int k0 = c * 32 + lg * 8;
            float4 u0 = *(const float4*)(xr + k0);
            float4 u1 = *(const float4*)(xr + k0 + 4);
            f16x8 a;
            a[0] = (_Float16)u0.x; a[1] = (_Float16)u0.y;
            a[2] = (_Float16)u0.z; a[3] = (_Float16)u0.w;
            a[4] = (_Float16)u1.x; a[5] = (_Float16)u1.y;
            a[6] = (_Float16)u1.z; a[7] = (_Float16)u1.w;
            afr[c] = a;
        }
    } else {
        const __half* xr = (const __half*)X + (size_t)arow * DIM;
        #pragma unroll
        for (int c = 0; c < 4; ++c) {
            U4H8 u; u.u = *(const uint4*)(xr + c * 32 + lg * 8);
            afr[c] = u.h;
        }
    }

    f32x4 acc[8];
    #pragma unroll
    for (int jt = 0; jt < 8; ++jt) acc[jt] = (f32x4){0.f, 0.f, 0.f, 0.f};

    #pragma unroll
    for (int c = 0; c < 4; ++c) {
        #pragma unroll
        for (int jt = 0; jt < 8; ++jt) {
            int col = jt * 16 + lr;
            int kb  = c * 64 + lg * 16;
            U4H8 b;
            b.u = *(const uint4*)(Wl + col * 256 + (kb ^ ((col & 7) << 4)));
            acc[jt] = __builtin_amdgcn_mfma_f32_16x16x32_f16(afr[c], b.h, acc[jt], 0, 0, 0);
        }
    }

    float4 dv = *(const float4*)(dis + slab * 16 + lg * 4);
    float dsc[4] = {dv.x, dv.y, dv.z, dv.w};
    #pragma unroll
    for (int j = 0; j < 4; ++j) {
        int row = slab * 16 + lg * 4 + j;
        __half* yr = Y + (size_t)row * DIM + lr;
        #pragma unroll
        for (int jt = 0; jt < 8; ++jt)
            yr[jt * 16] = (__half)(acc[jt][j] * dsc[j]);
    }
}

// ---------- GCN aggregate: fp16 gather-sum, fp32 accumulate, fp16 out ----------
__device__ __forceinline__ void acc_add(float4& a, uint2 u) {
    float2 f0 = __half22float2(*(__half2*)&u.x);
    float2 f1 = __half22float2(*(__half2*)&u.y);
    a.x += f0.x; a.y += f0.y; a.z += f1.x; a.w += f1.y;
}

__global__ void __launch_bounds__(256) gcn_gather(const __half* __restrict__ hwh,
                                                  const int* __restrict__ rowstart,
                                                  const int* __restrict__ csr_src,
                                                  const float* __restrict__ dis,
                                                  const float* __restrict__ b,
                                                  __half* __restrict__ outh) {
    int t = blockIdx.x * 256 + threadIdx.x;
    int d = t >> 5, q = t & 31;
    if (d >= NNODES) return;
    const uint2* hw8 = (const uint2*)hwh;

    float4 a0 = make_float4(0.f, 0.f, 0.f, 0.f);
    float4 a1 = a0, a2 = a0, a3 = a0, a4 = a0, a5 = a0, a6 = a0, a7 = a0;

    acc_add(a0, hw8[(size_t)d * 32 + q]);   // self-loop (pre-scaled)

    int beg = rowstart[d], end = rowstart[d + 1];
    int i = beg;
    for (; i + 8 <= end; i += 8) {
        int s0 = csr_src[i + 0], s1 = csr_src[i + 1];
        int s2 = csr_src[i + 2], s3 = csr_src[i + 3];
        int s4 = csr_src[i + 4], s5 = csr_src[i + 5];
        int s6 = csr_src[i + 6], s7 = csr_src[i + 7];
        uint2 v0 = hw8[(size_t)s0 * 32 + q];
        uint2 v1 = hw8[(size_t)s1 * 32 + q];
        uint2 v2 = hw8[(size_t)s2 * 32 + q];
        uint2 v3 = hw8[(size_t)s3 * 32 + q];
        uint2 v4 = hw8[(size_t)s4 * 32 + q];
        uint2 v5 = hw8[(size_t)s5 * 32 + q];
        uint2 v6 = hw8[(size_t)s6 * 32 + q];
        uint2 v7 = hw8[(size_t)s7 * 32 + q];
        acc_add(a0, v0); acc_add(a1, v1); acc_add(a2, v2); acc_add(a3, v3);
        acc_add(a4, v4); acc_add(a5, v5); acc_add(a6, v6); acc_add(a7, v7);
    }
    for (; i + 2 <= end; i += 2) {
        uint2 v0 = hw8[(size_t)csr_src[i + 0] * 32 + q];
        uint2 v1 = hw8[(size_t)csr_src[i + 1] * 32 + q];
        acc_add(a0, v0); acc_add(a1, v1);
    }
    if (i < end) acc_add(a0, hw8[(size_t)csr_src[i] * 32 + q]);

    a0.x += a1.x + a2.x + a3.x + a4.x + a5.x + a6.x + a7.x;
    a0.y += a1.y + a2.y + a3.y + a4.y + a5.y + a6.y + a7.y;
    a0.z += a1.z + a2.z + a3.z + a4.z + a5.z + a6.z + a7.z;
    a0.w += a1.w + a2.w + a3.w + a4.w + a5.w + a6.w + a7.w;

    float dd = dis[d];
    float4 bb = ((const float4*)b)[q];
    __half ot[4];
    ot[0] = (__half)fmaxf(fmaf(a0.x, dd, bb.x), 0.f);
    ot[1] = (__half)fmaxf(fmaf(a0.y, dd, bb.y), 0.f);
    ot[2] = (__half)fmaxf(fmaf(a0.z, dd, bb.z), 0.f);
    ot[3] = (__half)fmaxf(fmaf(a0.w, dd, bb.w), 0.f);
    ((uint2*)outh)[(size_t)d * 32 + q] = *(uint2*)ot;
}

// ---------- fused pooling + head: one 256-thread block per graph ----------
__device__ __forceinline__ int lower_bound_i(const int* __restrict__ a, int n, int v) {
    int lo = 0, hi = n;
    while (lo < hi) {
        int mid = (lo + hi) >> 1;
        if (a[mid] < v) lo = mid + 1; else hi = mid;
    }
    return lo;
}

__global__ void __launch_bounds__(256) pool_head(const __half* __restrict__ h,
                                                 const float* __restrict__ x,
                                                 const int* __restrict__ batch,
                                                 const int* __restrict__ xsrc,
                                                 const float* __restrict__ Wh,
                                                 const float* __restrict__ bh,
                                                 float* __restrict__ out) {
    __shared__ float sAG[DIM];
    __shared__ float sAC[DIM];
    __shared__ int   sSC;
    int g   = blockIdx.x;
    int t   = threadIdx.x;
    int sub = t >> 5;
    int q   = t & 31;

    if (t < DIM) { sAG[t] = 0.f; sAC[t] = 0.f; }
    if (t == 0) sSC = 0;
    __syncthreads();

    int lo = lower_bound_i(batch, NNODES, g);
    int hi = lower_bound_i(batch, NNODES, g + 1);

    float4 ag = make_float4(0.f, 0.f, 0.f, 0.f);
    float4 ac = make_float4(0.f, 0.f, 0.f, 0.f);
    int sc = 0;
    const uint2* h8 = (const uint2*)h;
    const float4* x4 = (const float4*)x;
    for (int r = lo + sub; r < hi; r += 8) {
        acc_add(ag, h8[(size_t)r * 32 + q]);
        if (xsrc[r] == 1) {
            float4 xv = x4[(size_t)r * 32 + q];
            ac.x += xv.x; ac.y += xv.y; ac.z += xv.z; ac.w += xv.w;
            sc++;
        }
    }
    float* agp = sAG + q * 4;
    atomicAdd(agp + 0, ag.x); atomicAdd(agp + 1, ag.y);
    atomicAdd(agp + 2, ag.z); atomicAdd(agp + 3, ag.w);
    float* acp = sAC + q * 4;
    atomicAdd(acp + 0, ac.x); atomicAdd(acp + 1, ac.y);
    atomicAdd(acp + 2, ac.z); atomicAdd(acp + 3, ac.w);
    if (q == 0 && sc) atomicAdd(&sSC, sc);
    __syncthreads();

    if (t < 32) {
        float invg = 1.0f / fmaxf((float)(hi - lo), 1.0f);
        float invc = 1.0f / fmaxf((float)sSC, 1.0f);
        const float2* Wh2 = (const float2*)Wh;
        float a0 = 0.f, a1 = 0.f;
        #pragma unroll
        for (int j = 0; j < 4; ++j) {
            float e1 = sAG[t * 4 + j] * invg;
            float2 w1 = Wh2[t * 4 + j];
            a0 = fmaf(e1, w1.x, a0);
            a1 = fmaf(e1, w1.y, a1);
            float e2 = sAC[t * 4 + j] * invc;
            float2 w2 = Wh2[DIM + t * 4 + j];
            a0 = fmaf(e2, w2.x, a0);
            a1 = fmaf(e2, w2.y, a1);
        }
        #pragma unroll
        for (int off = 16; off; off >>= 1) {
            a0 += __shfl_down(a0, off, 32);
            a1 += __shfl_down(a1, off, 32);
        }
        if (t == 0) {
            out[g * 2 + 0] = a0 + bh[0];
            out[g * 2 + 1] = a1 + bh[1];
        }
    }
}

extern "C" void kernel_launch(void* const* d_in, const int* in_sizes, int n_in,
                              void* d_out, int out_size, void* d_ws, size_t ws_size,
                              hipStream_t stream) {
    const float* x     = (const float*)d_in[0];
    const int*   ei    = (const int*)d_in[1];
    const int*   batch = (const int*)d_in[2];
    const int*   xsrc  = (const int*)d_in[3];
    const float* W1 = (const float*)d_in[4];
    const float* b1 = (const float*)d_in[5];
    const float* W2 = (const float*)d_in[6];
    const float* b2 = (const float*)d_in[7];
    const float* Wh = (const float*)d_in[8];
    const float* bh = (const float*)d_in[9];
    float* out = (float*)d_out;

    const int* src = ei;
    const int* dst = ei + NEDGES;

    // workspace layout (4-byte units)
    float* ws = (float*)d_ws;
    size_t off = 0;
    float*  dis      = ws + off;            off += 50048;
    int*    rowstart = (int*)(ws + off);    off += 50048;
    int*    deg      = (int*)(ws + off);    off += 50048;
    int*    part1    = (int*)(ws + off);    off += 256;
    int*    part2    = (int*)(ws + off);    off += 256;
    int*    pos      = (int*)(ws + off);    off += 800000;
    int*    csr_src  = (int*)(ws + off);    off += 800000;
    __half* Wt1      = (__half*)(ws + off); off += 8192;
    __half* Wt2      = (__half*)(ws + off); off += 8192;
    __half* hwh      = (__half*)(ws + off); off += (size_t)NNODES * DIM / 2;
    __half* hbuf     = (__half*)(ws + off); off += (size_t)NNODES * DIM / 2;

    const int n4 = NEDGES / 4;
    const int n8 = NEDGES / 8;

    // --- prep (deg zero + W transposes) + CSR build ---
    prep<<<(NNODES / 4 + 4096 + 255) / 256, 256, 0, stream>>>((int4*)deg, W1, W2, Wt1, Wt2);
    edge_pos<<<(n8 + 255) / 256, 256, 0, stream>>>((const int4*)dst, deg, (int4*)pos, n8);
    scan_block<<<NB_SCAN, 256, 0, stream>>>(deg, rowstart, part1, dis, NNODES);
    scan_partials<<<1, 256, 0, stream>>>(part1, part2, NB_SCAN);
    scan_add<<<NB_SCAN, 256, 0, stream>>>(rowstart, part2, NNODES);
    edge_scatter2<<<(n4 + 255) / 256, 256, 0, stream>>>((const int4*)src, (const int4*)dst,
                                                        (const int4*)pos, rowstart, csr_src, n4);

    const int ngemm = (NSLAB + 3) / 4;   // 782 blocks (4 waves/block)

    // --- layer 1: hwh = fp16((x@W1)*dis); h1 -> hbuf (fp16) ---
    gemm_mfma<float><<<ngemm, 256, 0, stream>>>(x, Wt1, dis, hwh);
    gcn_gather<<<(NNODES * 32) / 256, 256, 0, stream>>>(hwh, rowstart, csr_src, dis, b1, hbuf);

    // --- layer 2: hwh = fp16((h1@W2)*dis); h2 -> hbuf (fp16) ---
    gemm_mfma<__half><<<ngemm, 256, 0, stream>>>(hbuf, Wt2, dis, hwh);
    gcn_gather<<<(NNODES * 32) / 256, 256, 0, stream>>>(hwh, rowstart, csr_src, dis, b2, hbuf);

    // --- fused pooling + head ---
    pool_head<<<NGRAPH, 256, 0, stream>>>(hbuf, x, batch, xsrc, Wh, bh, out);
}

// Round 9
// 173.573 us; speedup vs baseline: 17.8596x; 1.0163x over previous
//
#include <hip/hip_runtime.h>
#include <hip/hip_fp16.h>

#define NNODES 50000
#define NEDGES 800000
#define DIM    128
#define NGRAPH 512
#define NB_SCAN 196   // ceil(50000/256)
#define NSLAB  3125   // 50000/16

typedef _Float16 f16x8 __attribute__((ext_vector_type(8)));
typedef float    f32x4 __attribute__((ext_vector_type(4)));
union U4H8 { uint4 u; f16x8 h; };

// ---------- prep: zero padded degree array (one counter per 64B line) + W->fp16 Wt[col][k] ----------
__global__ void prep(int4* __restrict__ degp4,
                     const float* __restrict__ W1, const float* __restrict__ W2,
                     __half* __restrict__ Wt1, __half* __restrict__ Wt2) {
    int t = blockIdx.x * 256 + threadIdx.x;
    if (t < NNODES * 4) { degp4[t] = make_int4(0, 0, 0, 0); return; }   // 50000*16 ints
    int i = t - NNODES * 4;
    if (i >= 4096) return;
    const float* W = (i < 2048) ? W1 : W2;
    __half* Wt = (i < 2048) ? Wt1 : Wt2;
    int j = i & 2047;
    int c  = j >> 4;          // output row = original col, 0..127
    int k0 = (j & 15) * 8;    // 8 k's per thread
    __half tmp[8];
    #pragma unroll
    for (int u = 0; u < 8; ++u) tmp[u] = (__half)W[(size_t)(k0 + u) * DIM + c];
    *(uint4*)(Wt + (size_t)c * DIM + k0) = *(uint4*)tmp;
}

// ---------- per-edge rank via return-atomics on line-padded counters ----------
__global__ void edge_pos(const int4* __restrict__ dst4, int* __restrict__ degp,
                         int4* __restrict__ pos4, int n4) {
    int t = blockIdx.x * blockDim.x + threadIdx.x;
    if (t >= n4) return;
    int4 d = dst4[t];
    int4 p;
    p.x = atomicAdd(&degp[d.x << 4], 1);
    p.y = atomicAdd(&degp[d.y << 4], 1);
    p.z = atomicAdd(&degp[d.z << 4], 1);
    p.w = atomicAdd(&degp[d.w << 4], 1);
    pos4[t] = p;
}

// ---------- exclusive scan (2 kernels); scan_block also emits dis = rsqrt(deg+1) ----------
__global__ void scan_block(const int* __restrict__ degp, int* __restrict__ out,
                           int* __restrict__ partials, float* __restrict__ dis, int n) {
    __shared__ int s[256];
    int t = threadIdx.x;
    int gid = blockIdx.x * 256 + t;
    int v = (gid < n) ? degp[gid << 4] : 0;
    if (gid < n) dis[gid] = rsqrtf((float)v + 1.0f);
    s[t] = v;
    __syncthreads();
    #pragma unroll
    for (int off = 1; off < 256; off <<= 1) {
        int u = (t >= off) ? s[t - off] : 0;
        __syncthreads();
        s[t] += u;
        __syncthreads();
    }
    if (gid < n) out[gid] = s[t] - v;          // exclusive within block
    if (t == 255) partials[blockIdx.x] = s[255];
}

__global__ void scan_partials(const int* __restrict__ in, int* __restrict__ out, int n) {
    __shared__ int s[256];
    int t = threadIdx.x;
    int v = (t < n) ? in[t] : 0;
    s[t] = v;
    __syncthreads();
    #pragma unroll
    for (int off = 1; off < 256; off <<= 1) {
        int u = (t >= off) ? s[t - off] : 0;
        __syncthreads();
        s[t] += u;
        __syncthreads();
    }
    if (t < n) out[t] = s[t] - v;
}

// ---------- atomic-free CSR scatter; rowstart finalized inline via part2 ----------
__global__ void edge_scatter2(const int4* __restrict__ src4, const int4* __restrict__ dst4,
                              const int4* __restrict__ pos4, const int* __restrict__ rowstart,
                              const int* __restrict__ part2, int* __restrict__ csr_src, int n4) {
    int t = blockIdx.x * blockDim.x + threadIdx.x;
    if (t >= n4) return;
    int4 s = src4[t];
    int4 d = dst4[t];
    int4 p = pos4[t];
    csr_src[rowstart[d.x] + part2[d.x >> 8] + p.x] = s.x;
    csr_src[rowstart[d.y] + part2[d.y >> 8] + p.y] = s.y;
    csr_src[rowstart[d.z] + part2[d.z >> 8] + p.z] = s.z;
    csr_src[rowstart[d.w] + part2[d.w >> 8] + p.w] = s.w;
}

// ---------- MFMA fp16 GEMM: Yh[row] = fp16((X @ W)[row] * dis[row]) ----------
template<typename XT>
__global__ void __launch_bounds__(256) gemm_mfma(const XT* __restrict__ X,
                                                 const __half* __restrict__ Wt,  // [128][128] fp16, Wt[col][k]
                                                 const float* __restrict__ dis,
                                                 __half* __restrict__ Y) {
    __shared__ __align__(16) unsigned char Wl[128 * 256];   // 32KB, XOR-swizzled rows

    const int t = threadIdx.x;
    {
        int col = t >> 1;
        int kb0 = (t & 1) * 128;
        const unsigned char* g = (const unsigned char*)Wt + col * 256 + kb0;
        #pragma unroll
        for (int i = 0; i < 8; ++i) {
            uint4 v = *(const uint4*)(g + i * 16);
            int kb = kb0 + i * 16;
            *(uint4*)(Wl + col * 256 + (kb ^ ((col & 7) << 4))) = v;
        }
    }
    __syncthreads();

    int wave = t >> 6;
    int slab = blockIdx.x * 4 + wave;
    if (slab >= NSLAB) return;
    int l  = t & 63;
    int lr = l & 15;        // A row within slab / D col
    int lg = l >> 4;        // k-group / D row-group

    int arow = slab * 16 + lr;

    f16x8 afr[4];
    if constexpr (sizeof(XT) == 4) {
        const float* xr = (const float*)X + (size_t)arow * DIM;
        #pragma unroll
        for (int c = 0; c < 4; ++c) {
            int k0 = c * 32 + lg * 8;
            float4 u0 = *(const float4*)(xr + k0);
            float4 u1 = *(const float4*)(xr + k0 + 4);
            f16x8 a;
            a[0] = (_Float16)u0.x; a[1] = (_Float16)u0.y;
            a[2] = (_Float16)u0.z; a[3] = (_Float16)u0.w;
            a[4] = (_Float16)u1.x; a[5] = (_Float16)u1.y;
            a[6] = (_Float16)u1.z; a[7] = (_Float16)u1.w;
            afr[c] = a;
        }
    } else {
        const __half* xr = (const __half*)X + (size_t)arow * DIM;
        #pragma unroll
        for (int c = 0; c < 4; ++c) {
            U4H8 u; u.u = *(const uint4*)(xr + c * 32 + lg * 8);
            afr[c] = u.h;
        }
    }

    f32x4 acc[8];
    #pragma unroll
    for (int jt = 0; jt < 8; ++jt) acc[jt] = (f32x4){0.f, 0.f, 0.f, 0.f};

    #pragma unroll
    for (int c = 0; c < 4; ++c) {
        #pragma unroll
        for (int jt = 0; jt < 8; ++jt) {
            int col = jt * 16 + lr;
            int kb  = c * 64 + lg * 16;
            U4H8 b;
            b.u = *(const uint4*)(Wl + col * 256 + (kb ^ ((col & 7) << 4)));
            acc[jt] = __builtin_amdgcn_mfma_f32_16x16x32_f16(afr[c], b.h, acc[jt], 0, 0, 0);
        }
    }

    float4 dv = *(const float4*)(dis + slab * 16 + lg * 4);
    float dsc[4] = {dv.x, dv.y, dv.z, dv.w};
    #pragma unroll
    for (int j = 0; j < 4; ++j) {
        int row = slab * 16 + lg * 4 + j;
        __half* yr = Y + (size_t)row * DIM + lr;
        #pragma unroll
        for (int jt = 0; jt < 8; ++jt)
            yr[jt * 16] = (__half)(acc[jt][j] * dsc[j]);
    }
}

// ---------- GCN aggregate: fp16 gather-sum, fp32 accumulate, fp16 out ----------
__device__ __forceinline__ void acc_add(float4& a, uint2 u) {
    float2 f0 = __half22float2(*(__half2*)&u.x);
    float2 f1 = __half22float2(*(__half2*)&u.y);
    a.x += f0.x; a.y += f0.y; a.z += f1.x; a.w += f1.y;
}

__global__ void __launch_bounds__(256) gcn_gather(const __half* __restrict__ hwh,
                                                  const int* __restrict__ rowstart,
                                                  const int* __restrict__ part2,
                                                  const int* __restrict__ csr_src,
                                                  const float* __restrict__ dis,
                                                  const float* __restrict__ b,
                                                  __half* __restrict__ outh) {
    int t = blockIdx.x * 256 + threadIdx.x;
    int d = t >> 5, q = t & 31;
    if (d >= NNODES) return;
    const uint2* hw8 = (const uint2*)hwh;

    float4 a0 = make_float4(0.f, 0.f, 0.f, 0.f);
    float4 a1 = a0, a2 = a0, a3 = a0, a4 = a0, a5 = a0, a6 = a0, a7 = a0;

    acc_add(a0, hw8[(size_t)d * 32 + q]);   // self-loop (pre-scaled)

    int beg = rowstart[d] + part2[d >> 8];
    int end = (d + 1 < NNODES) ? rowstart[d + 1] + part2[(d + 1) >> 8] : NEDGES;
    int i = beg;
    for (; i + 8 <= end; i += 8) {
        int s0 = csr_src[i + 0], s1 = csr_src[i + 1];
        int s2 = csr_src[i + 2], s3 = csr_src[i + 3];
        int s4 = csr_src[i + 4], s5 = csr_src[i + 5];
        int s6 = csr_src[i + 6], s7 = csr_src[i + 7];
        uint2 v0 = hw8[(size_t)s0 * 32 + q];
        uint2 v1 = hw8[(size_t)s1 * 32 + q];
        uint2 v2 = hw8[(size_t)s2 * 32 + q];
        uint2 v3 = hw8[(size_t)s3 * 32 + q];
        uint2 v4 = hw8[(size_t)s4 * 32 + q];
        uint2 v5 = hw8[(size_t)s5 * 32 + q];
        uint2 v6 = hw8[(size_t)s6 * 32 + q];
        uint2 v7 = hw8[(size_t)s7 * 32 + q];
        acc_add(a0, v0); acc_add(a1, v1); acc_add(a2, v2); acc_add(a3, v3);
        acc_add(a4, v4); acc_add(a5, v5); acc_add(a6, v6); acc_add(a7, v7);
    }
    for (; i + 2 <= end; i += 2) {
        uint2 v0 = hw8[(size_t)csr_src[i + 0] * 32 + q];
        uint2 v1 = hw8[(size_t)csr_src[i + 1] * 32 + q];
        acc_add(a0, v0); acc_add(a1, v1);
    }
    if (i < end) acc_add(a0, hw8[(size_t)csr_src[i] * 32 + q]);

    a0.x += a1.x + a2.x + a3.x + a4.x + a5.x + a6.x + a7.x;
    a0.y += a1.y + a2.y + a3.y + a4.y + a5.y + a6.y + a7.y;
    a0.z += a1.z + a2.z + a3.z + a4.z + a5.z + a6.z + a7.z;
    a0.w += a1.w + a2.w + a3.w + a4.w + a5.w + a6.w + a7.w;

    float dd = dis[d];
    float4 bb = ((const float4*)b)[q];
    __half ot[4];
    ot[0] = (__half)fmaxf(fmaf(a0.x, dd, bb.x), 0.f);
    ot[1] = (__half)fmaxf(fmaf(a0.y, dd, bb.y), 0.f);
    ot[2] = (__half)fmaxf(fmaf(a0.z, dd, bb.z), 0.f);
    ot[3] = (__half)fmaxf(fmaf(a0.w, dd, bb.w), 0.f);
    ((uint2*)outh)[(size_t)d * 32 + q] = *(uint2*)ot;
}

// ---------- fused pooling + head: one 256-thread block per graph ----------
__device__ __forceinline__ int lower_bound_i(const int* __restrict__ a, int n, int v) {
    int lo = 0, hi = n;
    while (lo < hi) {
        int mid = (lo + hi) >> 1;
        if (a[mid] < v) lo = mid + 1; else hi = mid;
    }
    return lo;
}

__global__ void __launch_bounds__(256) pool_head(const __half* __restrict__ h,
                                                 const float* __restrict__ x,
                                                 const int* __restrict__ batch,
                                                 const int* __restrict__ xsrc,
                                                 const float* __restrict__ Wh,
                                                 const float* __restrict__ bh,
                                                 float* __restrict__ out) {
    __shared__ float sAG[DIM];
    __shared__ float sAC[DIM];
    __shared__ int   sSC;
    int g   = blockIdx.x;
    int t   = threadIdx.x;
    int sub = t >> 5;
    int q   = t & 31;

    if (t < DIM) { sAG[t] = 0.f; sAC[t] = 0.f; }
    if (t == 0) sSC = 0;
    __syncthreads();

    int lo = lower_bound_i(batch, NNODES, g);
    int hi = lower_bound_i(batch, NNODES, g + 1);

    float4 ag = make_float4(0.f, 0.f, 0.f, 0.f);
    float4 ac = make_float4(0.f, 0.f, 0.f, 0.f);
    int sc = 0;
    const uint2* h8 = (const uint2*)h;
    const float4* x4 = (const float4*)x;
    for (int r = lo + sub; r < hi; r += 8) {
        acc_add(ag, h8[(size_t)r * 32 + q]);
        if (xsrc[r] == 1) {
            float4 xv = x4[(size_t)r * 32 + q];
            ac.x += xv.x; ac.y += xv.y; ac.z += xv.z; ac.w += xv.w;
            sc++;
        }
    }
    float* agp = sAG + q * 4;
    atomicAdd(agp + 0, ag.x); atomicAdd(agp + 1, ag.y);
    atomicAdd(agp + 2, ag.z); atomicAdd(agp + 3, ag.w);
    float* acp = sAC + q * 4;
    atomicAdd(acp + 0, ac.x); atomicAdd(acp + 1, ac.y);
    atomicAdd(acp + 2, ac.z); atomicAdd(acp + 3, ac.w);
    if (q == 0 && sc) atomicAdd(&sSC, sc);
    __syncthreads();

    if (t < 32) {
        float invg = 1.0f / fmaxf((float)(hi - lo), 1.0f);
        float invc = 1.0f / fmaxf((float)sSC, 1.0f);
        const float2* Wh2 = (const float2*)Wh;
        float a0 = 0.f, a1 = 0.f;
        #pragma unroll
        for (int j = 0; j < 4; ++j) {
            float e1 = sAG[t * 4 + j] * invg;
            float2 w1 = Wh2[t * 4 + j];
            a0 = fmaf(e1, w1.x, a0);
            a1 = fmaf(e1, w1.y, a1);
            float e2 = sAC[t * 4 + j] * invc;
            float2 w2 = Wh2[DIM + t * 4 + j];
            a0 = fmaf(e2, w2.x, a0);
            a1 = fmaf(e2, w2.y, a1);
        }
        #pragma unroll
        for (int off = 16; off; off >>= 1) {
            a0 += __shfl_down(a0, off, 32);
            a1 += __shfl_down(a1, off, 32);
        }
        if (t == 0) {
            out[g * 2 + 0] = a0 + bh[0];
            out[g * 2 + 1] = a1 + bh[1];
        }
    }
}

extern "C" void kernel_launch(void* const* d_in, const int* in_sizes, int n_in,
                              void* d_out, int out_size, void* d_ws, size_t ws_size,
                              hipStream_t stream) {
    const float* x     = (const float*)d_in[0];
    const int*   ei    = (const int*)d_in[1];
    const int*   batch = (const int*)d_in[2];
    const int*   xsrc  = (const int*)d_in[3];
    const float* W1 = (const float*)d_in[4];
    const float* b1 = (const float*)d_in[5];
    const float* W2 = (const float*)d_in[6];
    const float* b2 = (const float*)d_in[7];
    const float* Wh = (const float*)d_in[8];
    const float* bh = (const float*)d_in[9];
    float* out = (float*)d_out;

    const int* src = ei;
    const int* dst = ei + NEDGES;

    // workspace layout (4-byte units)
    float* ws = (float*)d_ws;
    size_t off = 0;
    float*  dis      = ws + off;            off += 50048;
    int*    rowstart = (int*)(ws + off);    off += 50048;
    int*    degp     = (int*)(ws + off);    off += NNODES * 16;   // line-padded counters
    int*    part1    = (int*)(ws + off);    off += 256;
    int*    part2    = (int*)(ws + off);    off += 256;
    int*    pos      = (int*)(ws + off);    off += 800000;
    int*    csr_src  = (int*)(ws + off);    off += 800000;
    __half* Wt1      = (__half*)(ws + off); off += 8192;
    __half* Wt2      = (__half*)(ws + off); off += 8192;
    __half* hwh      = (__half*)(ws + off); off += (size_t)NNODES * DIM / 2;
    __half* hbuf     = (__half*)(ws + off); off += (size_t)NNODES * DIM / 2;

    const int n4 = NEDGES / 4;   // 200000

    // --- prep (padded-deg zero + W transposes) + CSR build ---
    prep<<<(NNODES * 4 + 4096 + 255) / 256, 256, 0, stream>>>((int4*)degp, W1, W2, Wt1, Wt2);
    edge_pos<<<(n4 + 255) / 256, 256, 0, stream>>>((const int4*)dst, degp, (int4*)pos, n4);
    scan_block<<<NB_SCAN, 256, 0, stream>>>(degp, rowstart, part1, dis, NNODES);
    scan_partials<<<1, 256, 0, stream>>>(part1, part2, NB_SCAN);
    edge_scatter2<<<(n4 + 255) / 256, 256, 0, stream>>>((const int4*)src, (const int4*)dst,
                                                        (const int4*)pos, rowstart, part2,
                                                        csr_src, n4);

    const int ngemm = (NSLAB + 3) / 4;   // 782 blocks (4 waves/block)

    // --- layer 1: hwh = fp16((x@W1)*dis); h1 -> hbuf (fp16) ---
    gemm_mfma<float><<<ngemm, 256, 0, stream>>>(x, Wt1, dis, hwh);
    gcn_gather<<<(NNODES * 32) / 256, 256, 0, stream>>>(hwh, rowstart, part2, csr_src, dis, b1, hbuf);

    // --- layer 2: hwh = fp16((h1@W2)*dis); h2 -> hbuf (fp16) ---
    gemm_mfma<__half><<<ngemm, 256, 0, stream>>>(hbuf, Wt2, dis, hwh);
    gcn_gather<<<(NNODES * 32) / 256, 256, 0, stream>>>(hwh, rowstart, part2, csr_src, dis, b2, hbuf);

    // --- fused pooling + head ---
    pool_head<<<NGRAPH, 256, 0, stream>>>(hbuf, x, batch, xsrc, Wh, bh, out);
}